// Round 1
// baseline (947.601 us; speedup 1.0000x reference)
//
#include <hip/hip_runtime.h>
#include <hip/hip_bf16.h>

// DotProductAttention: B=16, Lq=Lk=2048, D=128, fp32 in/out.
// Round 0: correctness-first fp32 flash-attention baseline (vector ALU).
// Block = 256 threads handles one (batch, 32-query) tile; K/V tiles of 32
// staged in LDS; online softmax; P via LDS; O accumulated in registers.

#define B_    16
#define LQ    2048
#define LK    2048
#define DIM   128
#define QT    32      // query rows per block
#define KT    32      // key rows per tile
#define NTH   256
#define SCALE_ 0.08838834764831845f   // 1/sqrt(128)
#define NEGBIG -1.0e9f

__global__ __launch_bounds__(NTH, 2) void attn_fp32_flash(
    const float* __restrict__ Q, const float* __restrict__ K,
    const float* __restrict__ V, const float* __restrict__ Mk,
    float* __restrict__ O)
{
    // +4 pad keeps float4 alignment (stride 132 words = 33*16B)
    __shared__ float sQ[QT][DIM + 4];
    __shared__ float sK[KT][DIM + 4];
    __shared__ float sV[KT][DIM + 4];
    __shared__ float sP[QT][KT + 4];
    __shared__ float sM[KT];

    const int tid = threadIdx.x;
    const int tx  = tid & 15;    // 0..15: key-col group / d-col group
    const int ty  = tid >> 4;    // 0..15: q-row group (2 rows each)
    const int b   = blockIdx.x >> 6;          // 64 q-tiles per batch
    const int q0  = (blockIdx.x & 63) * QT;
    const int r0  = ty * 2;

    // ---- load Q tile (QT*DIM = 4096 floats = 1024 float4, coalesced) ----
    {
        const float4* Qg = (const float4*)(Q + ((size_t)b * LQ + q0) * DIM);
        #pragma unroll
        for (int it = 0; it < 4; ++it) {
            int i  = tid + it * NTH;
            int r  = i >> 5;          // 32 float4 per row
            int c4 = i & 31;
            *((float4*)&sQ[r][c4 * 4]) = Qg[r * 32 + c4];
        }
    }

    float m_i[2] = { -3.0e38f, -3.0e38f };
    float l_i[2] = { 0.f, 0.f };
    float o_acc[2][8];
    #pragma unroll
    for (int i = 0; i < 2; ++i)
        #pragma unroll
        for (int j = 0; j < 8; ++j) o_acc[i][j] = 0.f;

    for (int k0 = 0; k0 < LK; k0 += KT) {
        __syncthreads();   // previous PV done; sK/sV/sP reusable (also covers sQ on iter 0)

        // ---- stage K,V tile + mask (coalesced float4) ----
        const float4* Kg = (const float4*)(K + ((size_t)b * LK + k0) * DIM);
        const float4* Vg = (const float4*)(V + ((size_t)b * LK + k0) * DIM);
        #pragma unroll
        for (int it = 0; it < 4; ++it) {
            int i  = tid + it * NTH;
            int r  = i >> 5;
            int c4 = i & 31;
            *((float4*)&sK[r][c4 * 4]) = Kg[r * 32 + c4];
            *((float4*)&sV[r][c4 * 4]) = Vg[r * 32 + c4];
        }
        if (tid < KT) sM[tid] = Mk[k0 + tid];
        __syncthreads();

        // ---- scores: thread owns rows r0,r0+1  x  cols tx, tx+16 ----
        float s[2][2] = { {0.f, 0.f}, {0.f, 0.f} };
        #pragma unroll 4
        for (int d = 0; d < DIM; d += 4) {
            float4 qa = *(const float4*)&sQ[r0][d];
            float4 qb = *(const float4*)&sQ[r0 + 1][d];
            float4 k0v = *(const float4*)&sK[tx][d];
            float4 k1v = *(const float4*)&sK[tx + 16][d];
            s[0][0] += qa.x * k0v.x + qa.y * k0v.y + qa.z * k0v.z + qa.w * k0v.w;
            s[0][1] += qa.x * k1v.x + qa.y * k1v.y + qa.z * k1v.z + qa.w * k1v.w;
            s[1][0] += qb.x * k0v.x + qb.y * k0v.y + qb.z * k0v.z + qb.w * k0v.w;
            s[1][1] += qb.x * k1v.x + qb.y * k1v.y + qb.z * k1v.z + qb.w * k1v.w;
        }

        // scale + mask
        #pragma unroll
        for (int j = 0; j < 2; ++j) {
            float mb = sM[tx + 16 * j] * NEGBIG;
            s[0][j] = s[0][j] * SCALE_ + mb;
            s[1][j] = s[1][j] * SCALE_ + mb;
        }

        // ---- online softmax per q-row (row spread across the 16 tx lanes) ----
        #pragma unroll
        for (int i = 0; i < 2; ++i) {
            float mx = fmaxf(s[i][0], s[i][1]);
            #pragma unroll
            for (int off = 1; off < 16; off <<= 1)
                mx = fmaxf(mx, __shfl_xor(mx, off));
            float m_new = fmaxf(m_i[i], mx);
            float alpha = __expf(m_i[i] - m_new);
            float rs = 0.f;
            #pragma unroll
            for (int j = 0; j < 2; ++j) {
                float p = __expf(s[i][j] - m_new);
                sP[r0 + i][tx + 16 * j] = p;
                rs += p;
            }
            #pragma unroll
            for (int off = 1; off < 16; off <<= 1)
                rs += __shfl_xor(rs, off);
            l_i[i] = l_i[i] * alpha + rs;
            m_i[i] = m_new;
            #pragma unroll
            for (int j = 0; j < 8; ++j) o_acc[i][j] *= alpha;
        }
        __syncthreads();   // sP ready for all lanes

        // ---- PV: O[r][tx+16j] += sum_c P[r][c] * V[c][tx+16j] ----
        #pragma unroll 8
        for (int c = 0; c < KT; ++c) {
            float p0 = sP[r0][c];       // broadcast within ty group
            float p1 = sP[r0 + 1][c];
            #pragma unroll
            for (int j = 0; j < 8; ++j) {
                float v = sV[c][tx + 16 * j];   // conflict-free: bank = 4c+tx+16j
                o_acc[0][j] += p0 * v;
                o_acc[1][j] += p1 * v;
            }
        }
    }

    // ---- epilogue: normalize and write ----
    float* Og = O + ((size_t)b * LQ + q0) * DIM;
    #pragma unroll
    for (int i = 0; i < 2; ++i) {
        float inv = 1.0f / l_i[i];
        #pragma unroll
        for (int j = 0; j < 8; ++j)
            Og[(size_t)(r0 + i) * DIM + tx + 16 * j] = o_acc[i][j] * inv;
    }
}

extern "C" void kernel_launch(void* const* d_in, const int* in_sizes, int n_in,
                              void* d_out, int out_size, void* d_ws, size_t ws_size,
                              hipStream_t stream)
{
    const float* Q  = (const float*)d_in[0];
    const float* K  = (const float*)d_in[1];
    const float* V  = (const float*)d_in[2];
    const float* Mk = (const float*)d_in[3];
    float* O = (float*)d_out;

    dim3 grid(B_ * (LQ / QT));   // 16 * 64 = 1024 blocks
    dim3 block(NTH);
    hipLaunchKernelGGL(attn_fp32_flash, grid, block, 0, stream, Q, K, V, Mk, O);
}

// Round 2
// 274.938 us; speedup vs baseline: 3.4466x; 3.4466x over previous
//
#include <hip/hip_runtime.h>
#include <hip/hip_bf16.h>

// R1: bf16-MFMA flash attention. B=16, L=2048, D=128, fp32 in/out.
// Block = 256 thr (4 waves) x 64 q-rows; 64-key tiles; K rows + V^T staged
// bf16 in LDS; QK^T and PV via mfma_f32_16x16x32_bf16; online softmax in
// C-layout (col=lane&15, row=quad*4+reg); P through LDS (wave-private rows).
// LDS 62.7 KB -> exactly 2 blocks/CU; 512 blocks = full co-residency.

#define B_    16
#define LQ_   2048
#define LK_   2048
#define DIM_  128
#define QT_   64
#define KT_   64
#define NTH   256
#define SCALE_ 0.08838834764831845f   // 1/sqrt(128)
#define NEGBIG -1.0e9f

#define QS 136   // sQ/sK row stride in bf16 elems (272 B = 17*16B, odd multiple)
#define VS 72    // sVt/sP row stride (144 B = 9*16B, odd multiple)

typedef __attribute__((ext_vector_type(8))) short bf16x8;   // 8 bf16 = 4 VGPRs
typedef __attribute__((ext_vector_type(4))) float f32x4;

static __device__ __forceinline__ unsigned short f2bf(float f) {
    unsigned int u = __builtin_bit_cast(unsigned int, f);
    u += 0x7fff + ((u >> 16) & 1);          // round-to-nearest-even
    return (unsigned short)(u >> 16);
}

__global__ __launch_bounds__(NTH, 2) void attn_mfma_bf16(
    const float* __restrict__ Q, const float* __restrict__ K,
    const float* __restrict__ V, const float* __restrict__ Mk,
    float* __restrict__ O)
{
    __shared__ __align__(16) unsigned short sQ[QT_][QS];     // 17408 B
    __shared__ __align__(16) unsigned short sK[KT_][QS];     // 17408 B
    __shared__ __align__(16) unsigned short sVt[DIM_][VS];   // 18432 B  (V transposed)
    __shared__ __align__(16) unsigned short sP[QT_][VS];     //  9216 B
    __shared__ float sB[KT_];                                //   256 B  (additive bias)

    const int tid  = threadIdx.x;
    const int w    = tid >> 6;       // wave 0..3 -> q-rows [w*16, w*16+16)
    const int lane = tid & 63;
    const int quad = lane >> 4;      // 0..3
    const int l15  = lane & 15;

    // XCD-aware swizzle: xcd = bid&7 handles batches {xcd, xcd+8} only
    const int bid = blockIdx.x;
    const int grp = bid >> 3;
    const int b   = (bid & 7) + 8 * (grp & 1);
    const int q0  = (grp >> 1) * QT_;

    // ---- stage Q tile (fp32 -> bf16 rows), coalesced float4 ----
    {
        const float4* Qg = (const float4*)(Q + ((size_t)b * LQ_ + q0) * DIM_);
        #pragma unroll
        for (int it = 0; it < 8; ++it) {
            int i = tid + it * NTH;            // 0..2047
            int r = i >> 5, c4 = i & 31;
            float4 v = Qg[r * 32 + c4];
            ushort4 h = { f2bf(v.x), f2bf(v.y), f2bf(v.z), f2bf(v.w) };
            *(ushort4*)&sQ[r][c4 * 4] = h;
        }
    }
    __syncthreads();

    // Q A-fragments for this wave's 16 rows, kept in regs for all 32 k-iters.
    // A[m=lane&15][k=quad*8+j] -> contiguous 8 bf16 read.
    bf16x8 aQ[4];
    #pragma unroll
    for (int ks = 0; ks < 4; ++ks)
        aQ[ks] = *(const bf16x8*)&sQ[w * 16 + l15][ks * 32 + quad * 8];

    float m_i[4], l_i[4];
    f32x4 acc[8];
    #pragma unroll
    for (int r = 0; r < 4; ++r) { m_i[r] = -3.0e38f; l_i[r] = 0.f; }
    #pragma unroll
    for (int dt = 0; dt < 8; ++dt) acc[dt] = (f32x4){0.f, 0.f, 0.f, 0.f};

    for (int k0 = 0; k0 < LK_; k0 += KT_) {
        // ---- stage K rows + V transposed (bf16) ----
        const float4* Kg = (const float4*)(K + ((size_t)b * LK_ + k0) * DIM_);
        const float4* Vg = (const float4*)(V + ((size_t)b * LK_ + k0) * DIM_);
        #pragma unroll
        for (int it = 0; it < 8; ++it) {
            int i = tid + it * NTH;
            int r = i >> 5, c4 = i & 31;
            float4 kv = Kg[r * 32 + c4];
            ushort4 h = { f2bf(kv.x), f2bf(kv.y), f2bf(kv.z), f2bf(kv.w) };
            *(ushort4*)&sK[r][c4 * 4] = h;
            float4 vv = Vg[r * 32 + c4];
            int d = c4 * 4;
            sVt[d + 0][r] = f2bf(vv.x);
            sVt[d + 1][r] = f2bf(vv.y);
            sVt[d + 2][r] = f2bf(vv.z);
            sVt[d + 3][r] = f2bf(vv.w);
        }
        if (tid < KT_) sB[tid] = Mk[k0 + tid] * NEGBIG;
        __syncthreads();

        // ---- S = Q K^T: 4 key-tiles x 4 K-steps ----
        f32x4 s[4];
        #pragma unroll
        for (int kt = 0; kt < 4; ++kt) {
            f32x4 c = (f32x4){0.f, 0.f, 0.f, 0.f};
            #pragma unroll
            for (int ks = 0; ks < 4; ++ks) {
                bf16x8 bk = *(const bf16x8*)&sK[kt * 16 + l15][ks * 32 + quad * 8];
                c = __builtin_amdgcn_mfma_f32_16x16x32_bf16(aQ[ks], bk, c, 0, 0, 0);
            }
            float bias = sB[kt * 16 + l15];   // col (key) bias, same for all 4 rows
            #pragma unroll
            for (int r = 0; r < 4; ++r) s[kt][r] = c[r] * SCALE_ + bias;
        }

        // ---- online softmax; rows quad*4+r, reduce over quad's 16 lanes ----
        #pragma unroll
        for (int r = 0; r < 4; ++r) {
            float mx = fmaxf(fmaxf(s[0][r], s[1][r]), fmaxf(s[2][r], s[3][r]));
            #pragma unroll
            for (int off = 1; off < 16; off <<= 1) mx = fmaxf(mx, __shfl_xor(mx, off));
            float mn = fmaxf(m_i[r], mx);
            float al = __expf(m_i[r] - mn);
            m_i[r] = mn;
            float rs = 0.f;
            #pragma unroll
            for (int kt = 0; kt < 4; ++kt) {
                float p = __expf(s[kt][r] - mn);
                rs += p;
                sP[w * 16 + quad * 4 + r][kt * 16 + l15] = f2bf(p);
            }
            #pragma unroll
            for (int off = 1; off < 16; off <<= 1) rs += __shfl_xor(rs, off);
            l_i[r] = l_i[r] * al + rs;
            #pragma unroll
            for (int dt = 0; dt < 8; ++dt) acc[dt][r] *= al;   // per-row rescale
        }

        // ---- O += P V : A = P (LDS round-trip), B = V^T rows ----
        bf16x8 aP0 = *(const bf16x8*)&sP[w * 16 + l15][quad * 8];
        bf16x8 aP1 = *(const bf16x8*)&sP[w * 16 + l15][32 + quad * 8];
        #pragma unroll
        for (int dt = 0; dt < 8; ++dt) {
            bf16x8 bv0 = *(const bf16x8*)&sVt[dt * 16 + l15][quad * 8];
            bf16x8 bv1 = *(const bf16x8*)&sVt[dt * 16 + l15][32 + quad * 8];
            acc[dt] = __builtin_amdgcn_mfma_f32_16x16x32_bf16(aP0, bv0, acc[dt], 0, 0, 0);
            acc[dt] = __builtin_amdgcn_mfma_f32_16x16x32_bf16(aP1, bv1, acc[dt], 0, 0, 0);
        }
        __syncthreads();   // all waves done with sK/sVt before next stage
    }

    // ---- epilogue ----
    float* Og = O + ((size_t)b * LQ_ + q0 + w * 16) * DIM_;
    #pragma unroll
    for (int r = 0; r < 4; ++r) {
        float inv = 1.0f / l_i[r];
        int row = quad * 4 + r;
        #pragma unroll
        for (int dt = 0; dt < 8; ++dt)
            Og[(size_t)row * DIM_ + dt * 16 + l15] = acc[dt][r] * inv;
    }
}

extern "C" void kernel_launch(void* const* d_in, const int* in_sizes, int n_in,
                              void* d_out, int out_size, void* d_ws, size_t ws_size,
                              hipStream_t stream)
{
    const float* Q  = (const float*)d_in[0];
    const float* K  = (const float*)d_in[1];
    const float* V  = (const float*)d_in[2];
    const float* Mk = (const float*)d_in[3];
    float* O = (float*)d_out;

    dim3 grid(B_ * (LQ_ / QT_));   // 512 blocks
    dim3 block(NTH);
    hipLaunchKernelGGL(attn_mfma_bf16, grid, block, 0, stream, Q, K, V, Mk, O);
}

// Round 3
// 178.802 us; speedup vs baseline: 5.2997x; 1.5377x over previous
//
#include <hip/hip_runtime.h>
#include <hip/hip_bf16.h>

// R2: bf16-MFMA flash attention with ws pre-pass.
// Pre-pass packs Q,K (row tiles, chunk-swizzle c^(r&15)) and V^T (d-major,
// chunk-swizzle c^(d&7)) as bf16 "LDS-image" 16KB tiles in d_ws. Main kernel
// streams tiles with global_load_lds dwordx4 (linear copy), reads MFMA
// fragments conflict-free via the baked-in XOR swizzle.
// Block = 4 waves x 64 q-rows; 64-key tiles; online softmax in C-layout.

#define B_    16
#define LQ_   2048
#define LK_   2048
#define DIM_  128
#define NTH   256
#define SCALE_ 0.08838834764831845f   // 1/sqrt(128)
#define NEGBIG -1.0e9f
#define PS 72    // sP row stride in ushorts (144 B)

typedef __attribute__((ext_vector_type(8))) short bf16x8;
typedef __attribute__((ext_vector_type(4))) float f32x4;

#define GLDS(gsrc, ldst) \
  __builtin_amdgcn_global_load_lds( \
      (const __attribute__((address_space(1))) unsigned int*)(gsrc), \
      (__attribute__((address_space(3))) unsigned int*)(ldst), 16, 0, 0)

static __device__ __forceinline__ unsigned short f2bf(float f) {
    unsigned int u = __builtin_bit_cast(unsigned int, f);
    u += 0x7fff + ((u >> 16) & 1);          // RNE
    return (unsigned short)(u >> 16);
}

// ---- pre-pass 1: Q/K fp32 [B*L][128] -> bf16 tile image, swizzle c^(r&15) ----
// tile T (=b*32+t): row r(0..63), chunk c(0..15 of 16B): off = T*16384 + r*256 + (c^(r&15))*16
__global__ __launch_bounds__(NTH) void pack_qk(const float* __restrict__ src,
                                               unsigned short* __restrict__ dst)
{
    int gid = blockIdx.x * NTH + threadIdx.x;        // 0..524287
    int c = gid & 15, r = (gid >> 4) & 63;
    const float4* s4 = (const float4*)(src + (size_t)gid * 8);
    float4 a = s4[0], bq = s4[1];
    bf16x8 h = { (short)f2bf(a.x),  (short)f2bf(a.y),  (short)f2bf(a.z),  (short)f2bf(a.w),
                 (short)f2bf(bq.x), (short)f2bf(bq.y), (short)f2bf(bq.z), (short)f2bf(bq.w) };
    size_t doff = (size_t)(gid >> 10) * 8192 + r * 128 + ((c ^ (r & 15)) * 8);
    *(bf16x8*)(dst + doff) = h;
}

// ---- pre-pass 2: V fp32 -> V^T bf16 tile image, swizzle c^(d&7) ----
// tile T: row d(0..127) of 64 keys, chunk c(0..7): off = T*16384 + d*128 + (c^(d&7))*16
__global__ __launch_bounds__(NTH) void pack_vt(const float* __restrict__ V,
                                               unsigned short* __restrict__ dst)
{
    int T = blockIdx.x;                        // b*32 + ktile
    int w = threadIdx.x >> 6, lane = threadIdx.x & 63;
    const float* vb = V + (size_t)T * 64 * DIM_;
    unsigned short* db = dst + (size_t)T * 8192;
    #pragma unroll
    for (int half = 0; half < 2; ++half) {
        int d = half * 64 + lane;
        #pragma unroll
        for (int cb = 0; cb < 8; cb += 4) {
            int c = cb + w;
            float v[8];
            #pragma unroll
            for (int kk = 0; kk < 8; ++kk)      // coalesced: lanes = consecutive d
                v[kk] = vb[(size_t)(c * 8 + kk) * DIM_ + d];
            bf16x8 h = { (short)f2bf(v[0]), (short)f2bf(v[1]), (short)f2bf(v[2]), (short)f2bf(v[3]),
                         (short)f2bf(v[4]), (short)f2bf(v[5]), (short)f2bf(v[6]), (short)f2bf(v[7]) };
            *(bf16x8*)(db + d * 64 + ((c ^ (d & 7)) * 8)) = h;
        }
    }
}

// ---- main kernel ----
__global__ __launch_bounds__(NTH, 2) void attn_mfma2(
    const unsigned short* __restrict__ Qb, const unsigned short* __restrict__ Kb,
    const unsigned short* __restrict__ Vtb, const float* __restrict__ Mk,
    float* __restrict__ O)
{
    __shared__ __align__(16) unsigned short sQ[8192];
    __shared__ __align__(16) unsigned short sK[8192];
    __shared__ __align__(16) unsigned short sVt[8192];
    __shared__ __align__(16) unsigned short sP[64 * PS];
    __shared__ float sB[64];

    const int tid  = threadIdx.x;
    const int w    = tid >> 6, lane = tid & 63;
    const int quad = lane >> 4, l15 = lane & 15;

    const int bid = blockIdx.x;
    const int grp = bid >> 3;
    const int b   = (bid & 7) + 8 * (grp & 1);   // XCD-aware
    const int qt  = grp >> 1;                    // 0..31
    const int q0  = qt * 64;

    // ---- stage Q tile (16KB linear stream) ----
    {
        const char* qsrc = (const char*)Qb + (size_t)(b * 32 + qt) * 16384;
        #pragma unroll
        for (int j = 0; j < 4; ++j) {
            int o = (j * 4 + w) * 1024;
            GLDS(qsrc + o + lane * 16, (char*)sQ + o);
        }
    }
    __syncthreads();

    // Q A-fragments, kept in regs all 32 k-iters. A[m=l15][k=quad*8+j].
    bf16x8 aQ[4];
    #pragma unroll
    for (int ks = 0; ks < 4; ++ks) {
        int r = w * 16 + l15;
        int pc = (ks * 4 + quad) ^ l15;          // r&15 == l15
        aQ[ks] = *(const bf16x8*)&sQ[r * 128 + pc * 8];
    }

    float m_i[4], l_i[4];
    f32x4 acc[8];
    #pragma unroll
    for (int r = 0; r < 4; ++r) { m_i[r] = -3.0e38f; l_i[r] = 0.f; }
    #pragma unroll
    for (int dt = 0; dt < 8; ++dt) acc[dt] = (f32x4){0.f, 0.f, 0.f, 0.f};

    for (int k0 = 0; k0 < LK_; k0 += 64) {
        __syncthreads();   // prev tile's reads done before overwrite

        // ---- stage K + V^T tiles (2 x 16KB linear streams) ----
        const char* ksrc = (const char*)Kb  + (size_t)(b * 32 + (k0 >> 6)) * 16384;
        const char* vsrc = (const char*)Vtb + (size_t)(b * 32 + (k0 >> 6)) * 16384;
        #pragma unroll
        for (int j = 0; j < 4; ++j) {
            int o = (j * 4 + w) * 1024;
            GLDS(ksrc + o + lane * 16, (char*)sK + o);
            GLDS(vsrc + o + lane * 16, (char*)sVt + o);
        }
        if (tid < 64) sB[tid] = Mk[k0 + tid] * NEGBIG;
        __syncthreads();

        // ---- S = Q K^T ----
        f32x4 s[4];
        #pragma unroll
        for (int kt = 0; kt < 4; ++kt) {
            f32x4 c = (f32x4){0.f, 0.f, 0.f, 0.f};
            #pragma unroll
            for (int ks = 0; ks < 4; ++ks) {
                int r  = kt * 16 + l15;
                int pc = (ks * 4 + quad) ^ l15;
                bf16x8 bk = *(const bf16x8*)&sK[r * 128 + pc * 8];
                c = __builtin_amdgcn_mfma_f32_16x16x32_bf16(aQ[ks], bk, c, 0, 0, 0);
            }
            float bias = sB[kt * 16 + l15];
            #pragma unroll
            for (int r = 0; r < 4; ++r) s[kt][r] = c[r] * SCALE_ + bias;
        }

        // ---- online softmax (rows quad*4+r) ----
        #pragma unroll
        for (int r = 0; r < 4; ++r) {
            float mx = fmaxf(fmaxf(s[0][r], s[1][r]), fmaxf(s[2][r], s[3][r]));
            #pragma unroll
            for (int off = 1; off < 16; off <<= 1) mx = fmaxf(mx, __shfl_xor(mx, off));
            float mn = fmaxf(m_i[r], mx);
            float al = __expf(m_i[r] - mn);
            m_i[r] = mn;
            float rs = 0.f;
            #pragma unroll
            for (int kt = 0; kt < 4; ++kt) {
                float p = __expf(s[kt][r] - mn);
                rs += p;
                sP[(w * 16 + quad * 4 + r) * PS + kt * 16 + l15] = f2bf(p);
            }
            #pragma unroll
            for (int off = 1; off < 16; off <<= 1) rs += __shfl_xor(rs, off);
            l_i[r] = l_i[r] * al + rs;
            #pragma unroll
            for (int dt = 0; dt < 8; ++dt) acc[dt][r] *= al;
        }

        // ---- O += P V ----
        bf16x8 aP0 = *(const bf16x8*)&sP[(w * 16 + l15) * PS + quad * 8];
        bf16x8 aP1 = *(const bf16x8*)&sP[(w * 16 + l15) * PS + 32 + quad * 8];
        int pd = l15 & 7;
        #pragma unroll
        for (int dt = 0; dt < 8; ++dt) {
            int d = dt * 16 + l15;
            bf16x8 bv0 = *(const bf16x8*)&sVt[d * 64 + ((quad ^ pd) * 8)];
            bf16x8 bv1 = *(const bf16x8*)&sVt[d * 64 + (((quad + 4) ^ pd) * 8)];
            acc[dt] = __builtin_amdgcn_mfma_f32_16x16x32_bf16(aP0, bv0, acc[dt], 0, 0, 0);
            acc[dt] = __builtin_amdgcn_mfma_f32_16x16x32_bf16(aP1, bv1, acc[dt], 0, 0, 0);
        }
    }

    // ---- epilogue ----
    float* Og = O + ((size_t)b * LQ_ + q0 + w * 16) * DIM_;
    #pragma unroll
    for (int r = 0; r < 4; ++r) {
        float inv = 1.0f / l_i[r];
        int row = quad * 4 + r;
        #pragma unroll
        for (int dt = 0; dt < 8; ++dt)
            Og[(size_t)row * DIM_ + dt * 16 + l15] = acc[dt][r] * inv;
    }
}

// ================= fallback (R1 kernel, used if ws too small) =================
#define QS 136
#define VS 72
__global__ __launch_bounds__(NTH, 2) void attn_fallback(
    const float* __restrict__ Q, const float* __restrict__ K,
    const float* __restrict__ V, const float* __restrict__ Mk,
    float* __restrict__ O)
{
    __shared__ __align__(16) unsigned short sQ[64][QS];
    __shared__ __align__(16) unsigned short sK[64][QS];
    __shared__ __align__(16) unsigned short sVt[DIM_][VS];
    __shared__ __align__(16) unsigned short sP[64][VS];
    __shared__ float sB[64];

    const int tid  = threadIdx.x;
    const int w    = tid >> 6, lane = tid & 63;
    const int quad = lane >> 4, l15 = lane & 15;
    const int bid = blockIdx.x;
    const int grp = bid >> 3;
    const int b   = (bid & 7) + 8 * (grp & 1);
    const int q0  = (grp >> 1) * 64;

    {
        const float4* Qg = (const float4*)(Q + ((size_t)b * LQ_ + q0) * DIM_);
        #pragma unroll
        for (int it = 0; it < 8; ++it) {
            int i = tid + it * NTH;
            int r = i >> 5, c4 = i & 31;
            float4 v = Qg[r * 32 + c4];
            ushort4 h = { f2bf(v.x), f2bf(v.y), f2bf(v.z), f2bf(v.w) };
            *(ushort4*)&sQ[r][c4 * 4] = h;
        }
    }
    __syncthreads();
    bf16x8 aQ[4];
    #pragma unroll
    for (int ks = 0; ks < 4; ++ks)
        aQ[ks] = *(const bf16x8*)&sQ[w * 16 + l15][ks * 32 + quad * 8];

    float m_i[4], l_i[4];
    f32x4 acc[8];
    #pragma unroll
    for (int r = 0; r < 4; ++r) { m_i[r] = -3.0e38f; l_i[r] = 0.f; }
    #pragma unroll
    for (int dt = 0; dt < 8; ++dt) acc[dt] = (f32x4){0.f, 0.f, 0.f, 0.f};

    for (int k0 = 0; k0 < LK_; k0 += 64) {
        const float4* Kg = (const float4*)(K + ((size_t)b * LK_ + k0) * DIM_);
        const float4* Vg = (const float4*)(V + ((size_t)b * LK_ + k0) * DIM_);
        #pragma unroll
        for (int it = 0; it < 8; ++it) {
            int i = tid + it * NTH;
            int r = i >> 5, c4 = i & 31;
            float4 kv = Kg[r * 32 + c4];
            ushort4 h = { f2bf(kv.x), f2bf(kv.y), f2bf(kv.z), f2bf(kv.w) };
            *(ushort4*)&sK[r][c4 * 4] = h;
            float4 vv = Vg[r * 32 + c4];
            int d = c4 * 4;
            sVt[d + 0][r] = f2bf(vv.x);
            sVt[d + 1][r] = f2bf(vv.y);
            sVt[d + 2][r] = f2bf(vv.z);
            sVt[d + 3][r] = f2bf(vv.w);
        }
        if (tid < 64) sB[tid] = Mk[k0 + tid] * NEGBIG;
        __syncthreads();

        f32x4 s[4];
        #pragma unroll
        for (int kt = 0; kt < 4; ++kt) {
            f32x4 c = (f32x4){0.f, 0.f, 0.f, 0.f};
            #pragma unroll
            for (int ks = 0; ks < 4; ++ks) {
                bf16x8 bk = *(const bf16x8*)&sK[kt * 16 + l15][ks * 32 + quad * 8];
                c = __builtin_amdgcn_mfma_f32_16x16x32_bf16(aQ[ks], bk, c, 0, 0, 0);
            }
            float bias = sB[kt * 16 + l15];
            #pragma unroll
            for (int r = 0; r < 4; ++r) s[kt][r] = c[r] * SCALE_ + bias;
        }
        #pragma unroll
        for (int r = 0; r < 4; ++r) {
            float mx = fmaxf(fmaxf(s[0][r], s[1][r]), fmaxf(s[2][r], s[3][r]));
            #pragma unroll
            for (int off = 1; off < 16; off <<= 1) mx = fmaxf(mx, __shfl_xor(mx, off));
            float mn = fmaxf(m_i[r], mx);
            float al = __expf(m_i[r] - mn);
            m_i[r] = mn;
            float rs = 0.f;
            #pragma unroll
            for (int kt = 0; kt < 4; ++kt) {
                float p = __expf(s[kt][r] - mn);
                rs += p;
                sP[w * 16 + quad * 4 + r][kt * 16 + l15] = f2bf(p);
            }
            #pragma unroll
            for (int off = 1; off < 16; off <<= 1) rs += __shfl_xor(rs, off);
            l_i[r] = l_i[r] * al + rs;
            #pragma unroll
            for (int dt = 0; dt < 8; ++dt) acc[dt][r] *= al;
        }
        bf16x8 aP0 = *(const bf16x8*)&sP[w * 16 + l15][quad * 8];
        bf16x8 aP1 = *(const bf16x8*)&sP[w * 16 + l15][32 + quad * 8];
        #pragma unroll
        for (int dt = 0; dt < 8; ++dt) {
            bf16x8 bv0 = *(const bf16x8*)&sVt[dt * 16 + l15][quad * 8];
            bf16x8 bv1 = *(const bf16x8*)&sVt[dt * 16 + l15][32 + quad * 8];
            acc[dt] = __builtin_amdgcn_mfma_f32_16x16x32_bf16(aP0, bv0, acc[dt], 0, 0, 0);
            acc[dt] = __builtin_amdgcn_mfma_f32_16x16x32_bf16(aP1, bv1, acc[dt], 0, 0, 0);
        }
        __syncthreads();
    }
    float* Og = O + ((size_t)b * LQ_ + q0 + w * 16) * DIM_;
    #pragma unroll
    for (int r = 0; r < 4; ++r) {
        float inv = 1.0f / l_i[r];
        int row = quad * 4 + r;
        #pragma unroll
        for (int dt = 0; dt < 8; ++dt)
            Og[(size_t)row * DIM_ + dt * 16 + l15] = acc[dt][r] * inv;
    }
}

extern "C" void kernel_launch(void* const* d_in, const int* in_sizes, int n_in,
                              void* d_out, int out_size, void* d_ws, size_t ws_size,
                              hipStream_t stream)
{
    const float* Q  = (const float*)d_in[0];
    const float* K  = (const float*)d_in[1];
    const float* V  = (const float*)d_in[2];
    const float* Mk = (const float*)d_in[3];
    float* O = (float*)d_out;

    const size_t seg = (size_t)B_ * LQ_ * DIM_ * 2;   // 8 MB per packed tensor
    if (ws_size >= 3 * seg) {
        unsigned short* Qb  = (unsigned short*)d_ws;
        unsigned short* Kb  = Qb + seg / 2;
        unsigned short* Vtb = Kb + seg / 2;
        hipLaunchKernelGGL(pack_qk, dim3(2048), dim3(NTH), 0, stream, Q, Qb);
        hipLaunchKernelGGL(pack_qk, dim3(2048), dim3(NTH), 0, stream, K, Kb);
        hipLaunchKernelGGL(pack_vt, dim3(512),  dim3(NTH), 0, stream, V, Vtb);
        hipLaunchKernelGGL(attn_mfma2, dim3(512), dim3(NTH), 0, stream, Qb, Kb, Vtb, Mk, O);
    } else {
        hipLaunchKernelGGL(attn_fallback, dim3(512), dim3(NTH), 0, stream, Q, K, V, Mk, O);
    }
}

// Round 4
// 171.655 us; speedup vs baseline: 5.5204x; 1.0416x over previous
//
#include <hip/hip_runtime.h>
#include <hip/hip_bf16.h>

// R3: bf16-MFMA flash attention, LDS-read-optimized.
// Wave = 32 q-rows x 32 keys (B-frags reused across 2 row-sets -> LDS reads
// halved). Fixed-max softmax (M=12, exp2-folded): no running max / rescale;
// cross-wave l/O combine deferred to epilogue. Single fused pack kernel for
// K (row tiles, chunk^r swizzle) and V^T (chunk^d swizzle); Q converted
// in-kernel. Tiles streamed with global_load_lds dwordx4.

#define B_    16
#define LQ_   2048
#define LK_   2048
#define DIM_  128
#define NTH   256
#define SCALE_ 0.08838834764831845f          // 1/sqrt(128)
#define LOG2E_ 1.4426950408889634f
#define SC2_   (SCALE_ * LOG2E_)
#define MFIX_  12.0f
#define NEGBIG -1.0e9f
#define PS 72                                 // sP row stride (ushorts)

typedef __attribute__((ext_vector_type(8))) short bf16x8;
typedef __attribute__((ext_vector_type(4))) float f32x4;

#define GLDS(gsrc, ldst) \
  __builtin_amdgcn_global_load_lds( \
      (const __attribute__((address_space(1))) unsigned int*)(gsrc), \
      (__attribute__((address_space(3))) unsigned int*)(ldst), 16, 0, 0)

static __device__ __forceinline__ unsigned short f2bf(float f) {
    unsigned int u = __builtin_bit_cast(unsigned int, f);
    u += 0x7fff + ((u >> 16) & 1);          // RNE
    return (unsigned short)(u >> 16);
}

// ---- fused pre-pass: K row-tiles (c^(r&15)) + V^T tiles (c^(d&7)) ----
__global__ __launch_bounds__(NTH) void pack_kv(
    const float* __restrict__ K, const float* __restrict__ V,
    unsigned short* __restrict__ Kb, unsigned short* __restrict__ Vtb)
{
    int bid = blockIdx.x;
    if (bid < 2048) {
        int gid = bid * NTH + threadIdx.x;          // 0..524287, 8 floats each
        int c = gid & 15, r = (gid >> 4) & 63;
        const float4* s4 = (const float4*)(K + (size_t)gid * 8);
        float4 a = s4[0], bq = s4[1];
        bf16x8 h = { (short)f2bf(a.x),  (short)f2bf(a.y),  (short)f2bf(a.z),  (short)f2bf(a.w),
                     (short)f2bf(bq.x), (short)f2bf(bq.y), (short)f2bf(bq.z), (short)f2bf(bq.w) };
        size_t doff = (size_t)(gid >> 10) * 8192 + r * 128 + ((c ^ (r & 15)) * 8);
        *(bf16x8*)(Kb + doff) = h;
    } else {
        int T = bid - 2048;                         // 0..511 = b*32 + ktile
        int w = threadIdx.x >> 6, lane = threadIdx.x & 63;
        const float* vb = V + (size_t)T * 64 * DIM_;
        unsigned short* db = Vtb + (size_t)T * 8192;
        #pragma unroll
        for (int half = 0; half < 2; ++half) {
            int d = half * 64 + lane;
            #pragma unroll
            for (int cb = 0; cb < 8; cb += 4) {
                int c = cb + w;
                float v[8];
                #pragma unroll
                for (int kk = 0; kk < 8; ++kk)
                    v[kk] = vb[(size_t)(c * 8 + kk) * DIM_ + d];
                bf16x8 h = { (short)f2bf(v[0]), (short)f2bf(v[1]), (short)f2bf(v[2]), (short)f2bf(v[3]),
                             (short)f2bf(v[4]), (short)f2bf(v[5]), (short)f2bf(v[6]), (short)f2bf(v[7]) };
                *(bf16x8*)(db + d * 64 + ((c ^ (d & 7)) * 8)) = h;
            }
        }
    }
}

// ---- main kernel ----
__global__ __launch_bounds__(NTH, 2) void attn_mfma3(
    const float* __restrict__ Q, const unsigned short* __restrict__ Kb,
    const unsigned short* __restrict__ Vtb, const float* __restrict__ Mk,
    float* __restrict__ O)
{
    // manual carve: [0,16384) sK | [16384,32768) sVt | [32768,49152) sQ/sP
    // | [49152,49408) sB2 | [49408,49664) sLp ; epilogue sO = [0,32768)
    __shared__ __align__(16) char smem[49664];
    unsigned short* sK  = (unsigned short*)(smem);
    unsigned short* sVt = (unsigned short*)(smem + 16384);
    unsigned short* sQ  = (unsigned short*)(smem + 32768);
    unsigned short* sP  = (unsigned short*)(smem + 32768);
    float* sB2 = (float*)(smem + 49152);
    float* sLp = (float*)(smem + 49408);
    float* sO  = (float*)smem;

    const int tid  = threadIdx.x;
    const int w    = tid >> 6, lane = tid & 63;
    const int quad = lane >> 4, l15 = lane & 15;
    const int rg   = (w & 1) * 32;     // row group base (32 rows)
    const int wh   = w >> 1;           // key half 0/1
    const int kh   = wh * 32;          // key offset within 64-key tile

    const int bid = blockIdx.x;
    const int grp = bid >> 3;
    const int b   = (bid & 7) + 8 * (grp & 1);   // XCD-aware
    const int q0  = (grp >> 1) * 64;

    // ---- stage Q (fp32 -> swizzled bf16 in LDS) ----
    {
        const float4* Qg = (const float4*)(Q + ((size_t)b * LQ_ + q0) * DIM_);
        #pragma unroll
        for (int it = 0; it < 8; ++it) {
            int i = tid + it * NTH;            // 0..2047 float4s
            int r = i >> 5, c4 = i & 31;
            float4 v = Qg[r * 32 + c4];
            ushort4 h = { f2bf(v.x), f2bf(v.y), f2bf(v.z), f2bf(v.w) };
            *(ushort4*)&sQ[r * 128 + (((c4 >> 1) ^ (r & 15)) * 8) + (c4 & 1) * 4] = h;
        }
    }
    __syncthreads();

    // Q A-fragments: 2 row-sets x 4 k-steps, kept in regs all 32 iters.
    bf16x8 aQ[2][4];
    #pragma unroll
    for (int rs = 0; rs < 2; ++rs)
        #pragma unroll
        for (int ks = 0; ks < 4; ++ks)
            aQ[rs][ks] = *(const bf16x8*)&sQ[(rg + rs * 16 + l15) * 128 +
                                             (((ks * 4 + quad) ^ l15) * 8)];

    float l_i[2][4];
    f32x4 acc[2][8];
    #pragma unroll
    for (int rs = 0; rs < 2; ++rs) {
        #pragma unroll
        for (int r = 0; r < 4; ++r) l_i[rs][r] = 0.f;
        #pragma unroll
        for (int dt = 0; dt < 8; ++dt) acc[rs][dt] = (f32x4){0.f, 0.f, 0.f, 0.f};
    }

    for (int k0 = 0; k0 < LK_; k0 += 64) {
        __syncthreads();   // prev-iter LDS reads (and aQ loads) done

        const char* ksrc = (const char*)Kb  + (size_t)(b * 32 + (k0 >> 6)) * 16384;
        const char* vsrc = (const char*)Vtb + (size_t)(b * 32 + (k0 >> 6)) * 16384;
        #pragma unroll
        for (int j = 0; j < 4; ++j) {
            int o = (j * 4 + w) * 1024;
            GLDS(ksrc + o + lane * 16, smem + o);
            GLDS(vsrc + o + lane * 16, smem + 16384 + o);
        }
        if (tid < 64) sB2[tid] = (Mk[k0 + tid] * NEGBIG - MFIX_) * LOG2E_;
        __syncthreads();

        // ---- S = Q K^T : 2 key-subtiles x 4 k-steps, B reused for 2 row-sets
        f32x4 s_[2][2];
        #pragma unroll
        for (int kt2 = 0; kt2 < 2; ++kt2) {
            f32x4 c0 = (f32x4){0.f, 0.f, 0.f, 0.f};
            f32x4 c1 = (f32x4){0.f, 0.f, 0.f, 0.f};
            #pragma unroll
            for (int ks = 0; ks < 4; ++ks) {
                bf16x8 bk = *(const bf16x8*)&sK[(kh + kt2 * 16 + l15) * 128 +
                                                (((ks * 4 + quad) ^ l15) * 8)];
                c0 = __builtin_amdgcn_mfma_f32_16x16x32_bf16(aQ[0][ks], bk, c0, 0, 0, 0);
                c1 = __builtin_amdgcn_mfma_f32_16x16x32_bf16(aQ[1][ks], bk, c1, 0, 0, 0);
            }
            float bias = sB2[kh + kt2 * 16 + l15];
            #pragma unroll
            for (int r = 0; r < 4; ++r) {
                s_[0][kt2][r] = c0[r] * SC2_ + bias;
                s_[1][kt2][r] = c1[r] * SC2_ + bias;
            }
        }

        // ---- fixed-max softmax: p = exp2(s2); deferred-l row sums ----
        #pragma unroll
        for (int rs = 0; rs < 2; ++rs) {
            #pragma unroll
            for (int r = 0; r < 4; ++r) {
                float p0 = exp2f(s_[rs][0][r]);
                float p1 = exp2f(s_[rs][1][r]);
                int row = rg + rs * 16 + quad * 4 + r;
                sP[row * PS + kh + l15]      = f2bf(p0);
                sP[row * PS + kh + 16 + l15] = f2bf(p1);
                float v = p0 + p1;
                #pragma unroll
                for (int off = 1; off < 16; off <<= 1) v += __shfl_xor(v, off);
                l_i[rs][r] += v;
            }
        }

        // ---- O_partial += P V (wave's 32-key half), B reused for 2 row-sets
        bf16x8 aP0 = *(const bf16x8*)&sP[(rg + l15) * PS + kh + quad * 8];
        bf16x8 aP1 = *(const bf16x8*)&sP[(rg + 16 + l15) * PS + kh + quad * 8];
        #pragma unroll
        for (int dt = 0; dt < 8; ++dt) {
            int d = dt * 16 + l15;
            bf16x8 bv = *(const bf16x8*)&sVt[d * 64 + (((wh * 4 + quad) ^ (l15 & 7)) * 8)];
            acc[0][dt] = __builtin_amdgcn_mfma_f32_16x16x32_bf16(aP0, bv, acc[0][dt], 0, 0, 0);
            acc[1][dt] = __builtin_amdgcn_mfma_f32_16x16x32_bf16(aP1, bv, acc[1][dt], 0, 0, 0);
        }
    }

    // ---- epilogue: combine key-half partials (waves wh=1 publish via LDS) ----
    __syncthreads();
    if (wh == 1) {
        #pragma unroll
        for (int rs = 0; rs < 2; ++rs) {
            #pragma unroll
            for (int r = 0; r < 4; ++r) {
                int row = rg + rs * 16 + quad * 4 + r;
                #pragma unroll
                for (int dt = 0; dt < 8; ++dt)
                    sO[row * 128 + dt * 16 + l15] = acc[rs][dt][r];
                if (l15 == 0) sLp[row] = l_i[rs][r];
            }
        }
    }
    __syncthreads();
    if (wh == 0) {
        float* Og = O + ((size_t)b * LQ_ + q0) * DIM_;
        #pragma unroll
        for (int rs = 0; rs < 2; ++rs) {
            #pragma unroll
            for (int r = 0; r < 4; ++r) {
                int row = rg + rs * 16 + quad * 4 + r;
                float inv = 1.0f / (l_i[rs][r] + sLp[row]);
                #pragma unroll
                for (int dt = 0; dt < 8; ++dt)
                    Og[(size_t)row * DIM_ + dt * 16 + l15] =
                        (acc[rs][dt][r] + sO[row * 128 + dt * 16 + l15]) * inv;
            }
        }
    }
}

// ================= fallback (validated R1 kernel, ws too small) =============
#define QS 136
#define VS 72
__global__ __launch_bounds__(NTH, 2) void attn_fallback(
    const float* __restrict__ Q, const float* __restrict__ K,
    const float* __restrict__ V, const float* __restrict__ Mk,
    float* __restrict__ O)
{
    __shared__ __align__(16) unsigned short sQ[64][QS];
    __shared__ __align__(16) unsigned short sK[64][QS];
    __shared__ __align__(16) unsigned short sVt[DIM_][VS];
    __shared__ __align__(16) unsigned short sP[64][VS];
    __shared__ float sB[64];

    const int tid  = threadIdx.x;
    const int w    = tid >> 6, lane = tid & 63;
    const int quad = lane >> 4, l15 = lane & 15;
    const int bid = blockIdx.x;
    const int grp = bid >> 3;
    const int b   = (bid & 7) + 8 * (grp & 1);
    const int q0  = (grp >> 1) * 64;

    {
        const float4* Qg = (const float4*)(Q + ((size_t)b * LQ_ + q0) * DIM_);
        #pragma unroll
        for (int it = 0; it < 8; ++it) {
            int i = tid + it * NTH;
            int r = i >> 5, c4 = i & 31;
            float4 v = Qg[r * 32 + c4];
            ushort4 h = { f2bf(v.x), f2bf(v.y), f2bf(v.z), f2bf(v.w) };
            *(ushort4*)&sQ[r][c4 * 4] = h;
        }
    }
    __syncthreads();
    bf16x8 aQ[4];
    #pragma unroll
    for (int ks = 0; ks < 4; ++ks)
        aQ[ks] = *(const bf16x8*)&sQ[w * 16 + l15][ks * 32 + quad * 8];

    float m_i[4], l_i[4];
    f32x4 acc[8];
    #pragma unroll
    for (int r = 0; r < 4; ++r) { m_i[r] = -3.0e38f; l_i[r] = 0.f; }
    #pragma unroll
    for (int dt = 0; dt < 8; ++dt) acc[dt] = (f32x4){0.f, 0.f, 0.f, 0.f};

    for (int k0 = 0; k0 < LK_; k0 += 64) {
        const float4* Kg = (const float4*)(K + ((size_t)b * LK_ + k0) * DIM_);
        const float4* Vg = (const float4*)(V + ((size_t)b * LK_ + k0) * DIM_);
        #pragma unroll
        for (int it = 0; it < 8; ++it) {
            int i = tid + it * NTH;
            int r = i >> 5, c4 = i & 31;
            float4 kv = Kg[r * 32 + c4];
            ushort4 h = { f2bf(kv.x), f2bf(kv.y), f2bf(kv.z), f2bf(kv.w) };
            *(ushort4*)&sK[r][c4 * 4] = h;
            float4 vv = Vg[r * 32 + c4];
            int d = c4 * 4;
            sVt[d + 0][r] = f2bf(vv.x);
            sVt[d + 1][r] = f2bf(vv.y);
            sVt[d + 2][r] = f2bf(vv.z);
            sVt[d + 3][r] = f2bf(vv.w);
        }
        if (tid < 64) sB[tid] = Mk[k0 + tid] * NEGBIG;
        __syncthreads();

        f32x4 s[4];
        #pragma unroll
        for (int kt = 0; kt < 4; ++kt) {
            f32x4 c = (f32x4){0.f, 0.f, 0.f, 0.f};
            #pragma unroll
            for (int ks = 0; ks < 4; ++ks) {
                bf16x8 bk = *(const bf16x8*)&sK[kt * 16 + l15][ks * 32 + quad * 8];
                c = __builtin_amdgcn_mfma_f32_16x16x32_bf16(aQ[ks], bk, c, 0, 0, 0);
            }
            float bias = sB[kt * 16 + l15];
            #pragma unroll
            for (int r = 0; r < 4; ++r) s[kt][r] = c[r] * SCALE_ + bias;
        }
        #pragma unroll
        for (int r = 0; r < 4; ++r) {
            float mx = fmaxf(fmaxf(s[0][r], s[1][r]), fmaxf(s[2][r], s[3][r]));
            #pragma unroll
            for (int off = 1; off < 16; off <<= 1) mx = fmaxf(mx, __shfl_xor(mx, off));
            float mn = fmaxf(m_i[r], mx);
            float al = __expf(m_i[r] - mn);
            m_i[r] = mn;
            float rsum = 0.f;
            #pragma unroll
            for (int kt = 0; kt < 4; ++kt) {
                float p = __expf(s[kt][r] - mn);
                rsum += p;
                sP[w * 16 + quad * 4 + r][kt * 16 + l15] = f2bf(p);
            }
            #pragma unroll
            for (int off = 1; off < 16; off <<= 1) rsum += __shfl_xor(rsum, off);
            l_i[r] = l_i[r] * al + rsum;
            #pragma unroll
            for (int dt = 0; dt < 8; ++dt) acc[dt][r] *= al;
        }
        bf16x8 aP0 = *(const bf16x8*)&sP[w * 16 + l15][quad * 8];
        bf16x8 aP1 = *(const bf16x8*)&sP[w * 16 + l15][32 + quad * 8];
        #pragma unroll
        for (int dt = 0; dt < 8; ++dt) {
            bf16x8 bv0 = *(const bf16x8*)&sVt[dt * 16 + l15][quad * 8];
            bf16x8 bv1 = *(const bf16x8*)&sVt[dt * 16 + l15][32 + quad * 8];
            acc[dt] = __builtin_amdgcn_mfma_f32_16x16x32_bf16(aP0, bv0, acc[dt], 0, 0, 0);
            acc[dt] = __builtin_amdgcn_mfma_f32_16x16x32_bf16(aP1, bv1, acc[dt], 0, 0, 0);
        }
        __syncthreads();
    }
    float* Og = O + ((size_t)b * LQ_ + q0 + w * 16) * DIM_;
    #pragma unroll
    for (int r = 0; r < 4; ++r) {
        float inv = 1.0f / l_i[r];
        int row = quad * 4 + r;
        #pragma unroll
        for (int dt = 0; dt < 8; ++dt)
            Og[(size_t)row * DIM_ + dt * 16 + l15] = acc[dt][r] * inv;
    }
}

extern "C" void kernel_launch(void* const* d_in, const int* in_sizes, int n_in,
                              void* d_out, int out_size, void* d_ws, size_t ws_size,
                              hipStream_t stream)
{
    const float* Q  = (const float*)d_in[0];
    const float* K  = (const float*)d_in[1];
    const float* V  = (const float*)d_in[2];
    const float* Mk = (const float*)d_in[3];
    float* O = (float*)d_out;

    const size_t seg = (size_t)B_ * LK_ * DIM_ * 2;   // 8 MB per packed tensor
    if (ws_size >= 2 * seg) {
        unsigned short* Kb  = (unsigned short*)d_ws;
        unsigned short* Vtb = Kb + seg / 2;
        hipLaunchKernelGGL(pack_kv, dim3(2560), dim3(NTH), 0, stream, K, V, Kb, Vtb);
        hipLaunchKernelGGL(attn_mfma3, dim3(512), dim3(NTH), 0, stream, Q, Kb, Vtb, Mk, O);
    } else {
        hipLaunchKernelGGL(attn_fallback, dim3(512), dim3(NTH), 0, stream, Q, K, V, Mk, O);
    }
}

// Round 5
// 157.159 us; speedup vs baseline: 6.0296x; 1.0922x over previous
//
#include <hip/hip_runtime.h>
#include <hip/hip_bf16.h>

// R4: bf16-MFMA flash attention, software-pipelined double-buffered K/V.
// K-loop: issue global_load_lds for tile i+1 (into the OTHER buffer pair,
// distinct __shared__ symbols so no alias-ordering), compute tile i, ONE
// barrier. vmcnt(0) drain at the barrier lands after compute -> latency
// hidden. Softmax denominator via P*ones MFMA (no cross-lane shuffles).
// Wave = 32 q-rows x 32 keys; fixed-max exp2 softmax; key-half combine in
// epilogue. LDS 75.5 KB -> 2 blocks/CU.

#define B_    16
#define LQ_   2048
#define LK_   2048
#define DIM_  128
#define NTH   256
#define SCALE_ 0.08838834764831845f          // 1/sqrt(128)
#define LOG2E_ 1.4426950408889634f
#define SC2_   (SCALE_ * LOG2E_)
#define MFIX_  12.0f
#define NEGBIG -1.0e9f
#define PS 72                                 // sP row stride (ushorts)

typedef __attribute__((ext_vector_type(8))) short bf16x8;
typedef __attribute__((ext_vector_type(4))) float f32x4;

#define GLDS(gsrc, ldst) \
  __builtin_amdgcn_global_load_lds( \
      (const __attribute__((address_space(1))) unsigned int*)(gsrc), \
      (__attribute__((address_space(3))) unsigned int*)(ldst), 16, 0, 0)

static __device__ __forceinline__ unsigned short f2bf(float f) {
    unsigned int u = __builtin_bit_cast(unsigned int, f);
    u += 0x7fff + ((u >> 16) & 1);          // RNE
    return (unsigned short)(u >> 16);
}

// ---- fused pre-pass: K row-tiles (c^(r&15)) + V^T tiles (c^(d&7)) ----
__global__ __launch_bounds__(NTH) void pack_kv(
    const float* __restrict__ K, const float* __restrict__ V,
    unsigned short* __restrict__ Kb, unsigned short* __restrict__ Vtb)
{
    int bid = blockIdx.x;
    if (bid < 2048) {
        int gid = bid * NTH + threadIdx.x;          // 0..524287, 8 floats each
        int c = gid & 15, r = (gid >> 4) & 63;
        const float4* s4 = (const float4*)(K + (size_t)gid * 8);
        float4 a = s4[0], bq = s4[1];
        bf16x8 h = { (short)f2bf(a.x),  (short)f2bf(a.y),  (short)f2bf(a.z),  (short)f2bf(a.w),
                     (short)f2bf(bq.x), (short)f2bf(bq.y), (short)f2bf(bq.z), (short)f2bf(bq.w) };
        size_t doff = (size_t)(gid >> 10) * 8192 + r * 128 + ((c ^ (r & 15)) * 8);
        *(bf16x8*)(Kb + doff) = h;
    } else {
        int T = bid - 2048;                         // 0..511 = b*32 + ktile
        int w = threadIdx.x >> 6, lane = threadIdx.x & 63;
        const float* vb = V + (size_t)T * 64 * DIM_;
        unsigned short* db = Vtb + (size_t)T * 8192;
        #pragma unroll
        for (int half = 0; half < 2; ++half) {
            int d = half * 64 + lane;
            #pragma unroll
            for (int cb = 0; cb < 8; cb += 4) {
                int c = cb + w;
                float v[8];
                #pragma unroll
                for (int kk = 0; kk < 8; ++kk)
                    v[kk] = vb[(size_t)(c * 8 + kk) * DIM_ + d];
                bf16x8 h = { (short)f2bf(v[0]), (short)f2bf(v[1]), (short)f2bf(v[2]), (short)f2bf(v[3]),
                             (short)f2bf(v[4]), (short)f2bf(v[5]), (short)f2bf(v[6]), (short)f2bf(v[7]) };
                *(bf16x8*)(db + d * 64 + ((c ^ (d & 7)) * 8)) = h;
            }
        }
    }
}

// ---- main kernel ----
__global__ __launch_bounds__(NTH, 2) void attn_mfma4(
    const float* __restrict__ Q, const unsigned short* __restrict__ Kb,
    const unsigned short* __restrict__ Vtb, const float* __restrict__ Mk,
    float* __restrict__ O)
{
    // distinct symbols -> alias analysis separates prefetch writes from reads
    __shared__ __align__(16) unsigned short sKa[8192];
    __shared__ __align__(16) unsigned short sVta[8192];
    __shared__ __align__(16) unsigned short sKb_[8192];
    __shared__ __align__(16) unsigned short sVtb_[8192];
    __shared__ __align__(16) unsigned short sP[64 * PS];   // also Q-half staging
    __shared__ float sB2[2 * 64];
    __shared__ float sLp[64];

    const int tid  = threadIdx.x;
    const int w    = tid >> 6, lane = tid & 63;
    const int quad = lane >> 4, l15 = lane & 15;
    const int rg   = (w & 1) * 32;     // row group base (32 rows)
    const int wh   = w >> 1;           // key half 0/1
    const int kh   = wh * 32;

    const int bid = blockIdx.x;
    const int grp = bid >> 3;
    const int b   = (bid & 7) + 8 * (grp & 1);   // XCD-aware
    const int q0  = (grp >> 1) * 64;

    // ones B-fragment (bf16 1.0) for rowsum MFMA
    bf16x8 vone;
    #pragma unroll
    for (int j = 0; j < 8; ++j) vone[j] = (short)0x3F80;

    // ---- stage Q in two 32-row halves through sP region; load aQ frags ----
    bf16x8 aQ[2][4];
    {
        const float4* Qg = (const float4*)(Q + ((size_t)b * LQ_ + q0) * DIM_);
        #pragma unroll
        for (int h = 0; h < 2; ++h) {
            #pragma unroll
            for (int it = 0; it < 4; ++it) {
                int i2 = tid + it * NTH;          // 0..1023 float4s
                int r = i2 >> 5, c4 = i2 & 31;    // r = local row 0..31
                float4 v = Qg[(h * 32 + r) * 32 + c4];
                ushort4 hh = { f2bf(v.x), f2bf(v.y), f2bf(v.z), f2bf(v.w) };
                *(ushort4*)&sP[r * 128 + (((c4 >> 1) ^ (r & 15)) * 8) + (c4 & 1) * 4] = hh;
            }
            __syncthreads();
            if ((rg >> 5) == h) {
                #pragma unroll
                for (int rs = 0; rs < 2; ++rs)
                    #pragma unroll
                    for (int ks = 0; ks < 4; ++ks)
                        aQ[rs][ks] = *(const bf16x8*)&sP[(rs * 16 + l15) * 128 +
                                                         (((ks * 4 + quad) ^ l15) * 8)];
            }
            __syncthreads();
        }
    }

    // ---- prefetch tile 0 into buffer A + bias 0 ----
    {
        const char* ksrc = (const char*)Kb  + (size_t)(b * 32) * 16384;
        const char* vsrc = (const char*)Vtb + (size_t)(b * 32) * 16384;
        #pragma unroll
        for (int j = 0; j < 4; ++j) {
            int o = (j * 4 + w) * 1024;
            GLDS(ksrc + o + lane * 16, (char*)sKa + o);
            GLDS(vsrc + o + lane * 16, (char*)sVta + o);
        }
        if (tid < 64) sB2[tid] = (Mk[tid] * NEGBIG - MFIX_) * LOG2E_;
    }
    __syncthreads();   // drains vmcnt(0): tile 0 resident

    f32x4 acc[2][8], lacc[2];
    #pragma unroll
    for (int rs = 0; rs < 2; ++rs) {
        lacc[rs] = (f32x4){0.f, 0.f, 0.f, 0.f};
        #pragma unroll
        for (int dt = 0; dt < 8; ++dt) acc[rs][dt] = (f32x4){0.f, 0.f, 0.f, 0.f};
    }

#define TILE_BODY(CURK, CURV, NXTK, NXTV, I) do {                              \
    const int nxt = (I) + 1;                                                   \
    if (nxt < 32) {                                                            \
        const char* ksrc = (const char*)Kb  + (size_t)(b * 32 + nxt) * 16384;  \
        const char* vsrc = (const char*)Vtb + (size_t)(b * 32 + nxt) * 16384;  \
        _Pragma("unroll")                                                      \
        for (int j = 0; j < 4; ++j) {                                          \
            int o = (j * 4 + w) * 1024;                                        \
            GLDS(ksrc + o + lane * 16, (char*)(NXTK) + o);                     \
            GLDS(vsrc + o + lane * 16, (char*)(NXTV) + o);                     \
        }                                                                      \
        if (tid < 64)                                                          \
            sB2[(nxt & 1) * 64 + tid] =                                        \
                (Mk[nxt * 64 + tid] * NEGBIG - MFIX_) * LOG2E_;                \
    }                                                                          \
    f32x4 s_[2][2];                                                            \
    _Pragma("unroll")                                                          \
    for (int kt2 = 0; kt2 < 2; ++kt2) {                                        \
        f32x4 c0 = (f32x4){0.f,0.f,0.f,0.f}, c1 = (f32x4){0.f,0.f,0.f,0.f};   \
        _Pragma("unroll")                                                      \
        for (int ks = 0; ks < 4; ++ks) {                                       \
            bf16x8 bk = *(const bf16x8*)&(CURK)[(kh + kt2 * 16 + l15) * 128 +  \
                                                (((ks * 4 + quad) ^ l15) * 8)];\
            c0 = __builtin_amdgcn_mfma_f32_16x16x32_bf16(aQ[0][ks], bk, c0, 0,0,0); \
            c1 = __builtin_amdgcn_mfma_f32_16x16x32_bf16(aQ[1][ks], bk, c1, 0,0,0); \
        }                                                                      \
        float bias = sB2[((I) & 1) * 64 + kh + kt2 * 16 + l15];                \
        _Pragma("unroll")                                                      \
        for (int r = 0; r < 4; ++r) {                                          \
            s_[0][kt2][r] = c0[r] * SC2_ + bias;                               \
            s_[1][kt2][r] = c1[r] * SC2_ + bias;                               \
        }                                                                      \
    }                                                                          \
    _Pragma("unroll")                                                          \
    for (int rs = 0; rs < 2; ++rs)                                             \
        _Pragma("unroll")                                                      \
        for (int r = 0; r < 4; ++r) {                                          \
            int row = rg + rs * 16 + quad * 4 + r;                             \
            sP[row * PS + kh + l15]      = f2bf(exp2f(s_[rs][0][r]));          \
            sP[row * PS + kh + 16 + l15] = f2bf(exp2f(s_[rs][1][r]));          \
        }                                                                      \
    {                                                                          \
        bf16x8 aP0 = *(const bf16x8*)&sP[(rg + l15) * PS + kh + quad * 8];     \
        bf16x8 aP1 = *(const bf16x8*)&sP[(rg + 16 + l15) * PS + kh + quad * 8];\
        lacc[0] = __builtin_amdgcn_mfma_f32_16x16x32_bf16(aP0, vone, lacc[0], 0,0,0); \
        lacc[1] = __builtin_amdgcn_mfma_f32_16x16x32_bf16(aP1, vone, lacc[1], 0,0,0); \
        _Pragma("unroll")                                                      \
        for (int dt = 0; dt < 8; ++dt) {                                       \
            int d = dt * 16 + l15;                                             \
            bf16x8 bv = *(const bf16x8*)&(CURV)[d * 64 +                       \
                                        (((wh * 4 + quad) ^ (l15 & 7)) * 8)];  \
            acc[0][dt] = __builtin_amdgcn_mfma_f32_16x16x32_bf16(aP0, bv, acc[0][dt], 0,0,0); \
            acc[1][dt] = __builtin_amdgcn_mfma_f32_16x16x32_bf16(aP1, bv, acc[1][dt], 0,0,0); \
        }                                                                      \
    }                                                                          \
    __syncthreads();                                                           \
} while (0)

    for (int kk = 0; kk < 32; kk += 2) {
        TILE_BODY(sKa,  sVta,  sKb_, sVtb_, kk);
        TILE_BODY(sKb_, sVtb_, sKa,  sVta,  kk + 1);
    }
#undef TILE_BODY

    // ---- epilogue: combine key-half partials (wh=1 publishes via LDS) ----
    float* sOw = (rg == 0) ? (float*)sKa : (float*)sVta;   // 32 rows x 128 f32
    if (wh == 1) {
        #pragma unroll
        for (int rs = 0; rs < 2; ++rs)
            #pragma unroll
            for (int r = 0; r < 4; ++r) {
                int lrow = rs * 16 + quad * 4 + r;
                #pragma unroll
                for (int dt = 0; dt < 8; ++dt)
                    sOw[lrow * 128 + dt * 16 + l15] = acc[rs][dt][r];
                if (l15 == 0) sLp[rg + lrow] = lacc[rs][r];
            }
    }
    __syncthreads();
    if (wh == 0) {
        float* Og = O + ((size_t)b * LQ_ + q0 + rg) * DIM_;
        #pragma unroll
        for (int rs = 0; rs < 2; ++rs)
            #pragma unroll
            for (int r = 0; r < 4; ++r) {
                int lrow = rs * 16 + quad * 4 + r;
                float inv = 1.0f / (lacc[rs][r] + sLp[rg + lrow]);
                #pragma unroll
                for (int dt = 0; dt < 8; ++dt)
                    Og[(size_t)lrow * DIM_ + dt * 16 + l15] =
                        (acc[rs][dt][r] + sOw[lrow * 128 + dt * 16 + l15]) * inv;
            }
    }
}

// ================= fallback (validated R1 kernel, ws too small) =============
#define QS 136
#define VS 72
__global__ __launch_bounds__(NTH, 2) void attn_fallback(
    const float* __restrict__ Q, const float* __restrict__ K,
    const float* __restrict__ V, const float* __restrict__ Mk,
    float* __restrict__ O)
{
    __shared__ __align__(16) unsigned short sQ[64][QS];
    __shared__ __align__(16) unsigned short sK[64][QS];
    __shared__ __align__(16) unsigned short sVt[DIM_][VS];
    __shared__ __align__(16) unsigned short sPf[64][VS];
    __shared__ float sB[64];

    const int tid  = threadIdx.x;
    const int w    = tid >> 6, lane = tid & 63;
    const int quad = lane >> 4, l15 = lane & 15;
    const int bid = blockIdx.x;
    const int grp = bid >> 3;
    const int b   = (bid & 7) + 8 * (grp & 1);
    const int q0  = (grp >> 1) * 64;

    {
        const float4* Qg = (const float4*)(Q + ((size_t)b * LQ_ + q0) * DIM_);
        #pragma unroll
        for (int it = 0; it < 8; ++it) {
            int i = tid + it * NTH;
            int r = i >> 5, c4 = i & 31;
            float4 v = Qg[r * 32 + c4];
            ushort4 h = { f2bf(v.x), f2bf(v.y), f2bf(v.z), f2bf(v.w) };
            *(ushort4*)&sQ[r][c4 * 4] = h;
        }
    }
    __syncthreads();
    bf16x8 aQ[4];
    #pragma unroll
    for (int ks = 0; ks < 4; ++ks)
        aQ[ks] = *(const bf16x8*)&sQ[w * 16 + l15][ks * 32 + quad * 8];

    float m_i[4], l_i[4];
    f32x4 acc[8];
    #pragma unroll
    for (int r = 0; r < 4; ++r) { m_i[r] = -3.0e38f; l_i[r] = 0.f; }
    #pragma unroll
    for (int dt = 0; dt < 8; ++dt) acc[dt] = (f32x4){0.f, 0.f, 0.f, 0.f};

    for (int k0 = 0; k0 < LK_; k0 += 64) {
        const float4* Kg = (const float4*)(K + ((size_t)b * LK_ + k0) * DIM_);
        const float4* Vg = (const float4*)(V + ((size_t)b * LK_ + k0) * DIM_);
        #pragma unroll
        for (int it = 0; it < 8; ++it) {
            int i = tid + it * NTH;
            int r = i >> 5, c4 = i & 31;
            float4 kv = Kg[r * 32 + c4];
            ushort4 h = { f2bf(kv.x), f2bf(kv.y), f2bf(kv.z), f2bf(kv.w) };
            *(ushort4*)&sK[r][c4 * 4] = h;
            float4 vv = Vg[r * 32 + c4];
            int d = c4 * 4;
            sVt[d + 0][r] = f2bf(vv.x);
            sVt[d + 1][r] = f2bf(vv.y);
            sVt[d + 2][r] = f2bf(vv.z);
            sVt[d + 3][r] = f2bf(vv.w);
        }
        if (tid < 64) sB[tid] = Mk[k0 + tid] * NEGBIG;
        __syncthreads();

        f32x4 s[4];
        #pragma unroll
        for (int kt = 0; kt < 4; ++kt) {
            f32x4 c = (f32x4){0.f, 0.f, 0.f, 0.f};
            #pragma unroll
            for (int ks = 0; ks < 4; ++ks) {
                bf16x8 bk = *(const bf16x8*)&sK[kt * 16 + l15][ks * 32 + quad * 8];
                c = __builtin_amdgcn_mfma_f32_16x16x32_bf16(aQ[ks], bk, c, 0, 0, 0);
            }
            float bias = sB[kt * 16 + l15];
            #pragma unroll
            for (int r = 0; r < 4; ++r) s[kt][r] = c[r] * SCALE_ + bias;
        }
        #pragma unroll
        for (int r = 0; r < 4; ++r) {
            float mx = fmaxf(fmaxf(s[0][r], s[1][r]), fmaxf(s[2][r], s[3][r]));
            #pragma unroll
            for (int off = 1; off < 16; off <<= 1) mx = fmaxf(mx, __shfl_xor(mx, off));
            float mn = fmaxf(m_i[r], mx);
            float al = __expf(m_i[r] - mn);
            m_i[r] = mn;
            float rsum = 0.f;
            #pragma unroll
            for (int kt = 0; kt < 4; ++kt) {
                float p = __expf(s[kt][r] - mn);
                rsum += p;
                sPf[w * 16 + quad * 4 + r][kt * 16 + l15] = f2bf(p);
            }
            #pragma unroll
            for (int off = 1; off < 16; off <<= 1) rsum += __shfl_xor(rsum, off);
            l_i[r] = l_i[r] * al + rsum;
            #pragma unroll
            for (int dt = 0; dt < 8; ++dt) acc[dt][r] *= al;
        }
        bf16x8 aP0 = *(const bf16x8*)&sPf[w * 16 + l15][quad * 8];
        bf16x8 aP1 = *(const bf16x8*)&sPf[w * 16 + l15][32 + quad * 8];
        #pragma unroll
        for (int dt = 0; dt < 8; ++dt) {
            bf16x8 bv0 = *(const bf16x8*)&sVt[dt * 16 + l15][quad * 8];
            bf16x8 bv1 = *(const bf16x8*)&sVt[dt * 16 + l15][32 + quad * 8];
            acc[dt] = __builtin_amdgcn_mfma_f32_16x16x32_bf16(aP0, bv0, acc[dt], 0, 0, 0);
            acc[dt] = __builtin_amdgcn_mfma_f32_16x16x32_bf16(aP1, bv1, acc[dt], 0, 0, 0);
        }
        __syncthreads();
    }
    float* Og = O + ((size_t)b * LQ_ + q0 + w * 16) * DIM_;
    #pragma unroll
    for (int r = 0; r < 4; ++r) {
        float inv = 1.0f / l_i[r];
        int row = quad * 4 + r;
        #pragma unroll
        for (int dt = 0; dt < 8; ++dt)
            Og[(size_t)row * DIM_ + dt * 16 + l15] = acc[dt][r] * inv;
    }
}

extern "C" void kernel_launch(void* const* d_in, const int* in_sizes, int n_in,
                              void* d_out, int out_size, void* d_ws, size_t ws_size,
                              hipStream_t stream)
{
    const float* Q  = (const float*)d_in[0];
    const float* K  = (const float*)d_in[1];
    const float* V  = (const float*)d_in[2];
    const float* Mk = (const float*)d_in[3];
    float* O = (float*)d_out;

    const size_t seg = (size_t)B_ * LK_ * DIM_ * 2;   // 8 MB per packed tensor
    if (ws_size >= 2 * seg) {
        unsigned short* Kb  = (unsigned short*)d_ws;
        unsigned short* Vtb = Kb + seg / 2;
        hipLaunchKernelGGL(pack_kv, dim3(2560), dim3(NTH), 0, stream, K, V, Kb, Vtb);
        hipLaunchKernelGGL(attn_mfma4, dim3(512), dim3(NTH), 0, stream, Q, Kb, Vtb, Mk, O);
    } else {
        hipLaunchKernelGGL(attn_fallback, dim3(512), dim3(NTH), 0, stream, Q, K, V, Mk, O);
    }
}

// Round 6
// 151.117 us; speedup vs baseline: 6.2706x; 1.0400x over previous
//
#include <hip/hip_runtime.h>
#include <hip/hip_bf16.h>

// R6: bf16-MFMA flash attention + masked-key compaction.
// mask is query-independent: masked keys (~20%) contribute exactly 0 in fp32
// reference (exp(-1e9)=0), so we compact them away: build_idx computes the
// kept-key list; pack_kv gathers only kept keys into swizzled bf16 tiles
// (K rows key-interleaved so each lane's two P values are adjacent keys ->
// single v_perm pack + ds_write_b32); main kernel runs ceil(cnt/64) tiles
// with bias = register compare (no mask LDS). Q pre-scaled by 1/sqrt(d)*log2e.
// Double-buffered GLDS pipeline as R5 (distinct __shared__ symbols).

#define B_    16
#define LQ_   2048
#define LK_   2048
#define DIM_  128
#define NTH   256
#define SCALE_ 0.08838834764831845f          // 1/sqrt(128)
#define LOG2E_ 1.4426950408889634f
#define SC2_   (SCALE_ * LOG2E_)
#define MFIX_  12.0f
#define CKEEP_ (-MFIX_ * LOG2E_)
#define CMASK_ (-1.0e30f)
#define NEGBIG -1.0e9f
#define PS 72                                 // sP row stride (ushorts)

typedef __attribute__((ext_vector_type(8))) short bf16x8;
typedef __attribute__((ext_vector_type(4))) float f32x4;

#define GLDS(gsrc, ldst) \
  __builtin_amdgcn_global_load_lds( \
      (const __attribute__((address_space(1))) unsigned int*)(gsrc), \
      (__attribute__((address_space(3))) unsigned int*)(ldst), 16, 0, 0)

static __device__ __forceinline__ unsigned short f2bf(float f) {
    unsigned int u = __builtin_bit_cast(unsigned int, f);
    u += 0x7fff + ((u >> 16) & 1);          // RNE
    return (unsigned short)(u >> 16);
}

// ---- kernel 1: kept-key index list (mask==0 kept), 1 block ----
__global__ __launch_bounds__(256) void build_idx(const float* __restrict__ Mk,
                                                 int* __restrict__ hdr,
                                                 int* __restrict__ idx)
{
    __shared__ int sc[256];
    int t = threadIdx.x;
    int keep[8], loc[8];
    int c = 0;
    #pragma unroll
    for (int j = 0; j < 8; ++j) {
        keep[j] = (Mk[t * 8 + j] < 0.5f) ? 1 : 0;
        loc[j] = c;
        c += keep[j];
    }
    sc[t] = c;
    __syncthreads();
    for (int off = 1; off < 256; off <<= 1) {     // Hillis-Steele inclusive
        int v = (t >= off) ? sc[t - off] : 0;
        __syncthreads();
        sc[t] += v;
        __syncthreads();
    }
    int base = sc[t] - c;                          // exclusive prefix
    #pragma unroll
    for (int j = 0; j < 8; ++j)
        if (keep[j]) idx[base + loc[j]] = t * 8 + j;
    if (t == 255) hdr[0] = sc[255];
}

// ---- kernel 2: gather-pack kept K rows (key-interleaved, chunk^row swizzle)
//      + V^T tiles (chunk^d swizzle). Slots >= cnt fall back to key 0 (their
//      P is forced to 0 by the bias compare in the main kernel). ----
__global__ __launch_bounds__(NTH) void pack_kv(
    const float* __restrict__ K, const float* __restrict__ V,
    const int* __restrict__ hdr, const int* __restrict__ idx,
    unsigned short* __restrict__ Kb, unsigned short* __restrict__ Vtb)
{
    const int cnt = hdr[0];
    int bid = blockIdx.x;
    if (bid < 2048) {
        int gid = bid * NTH + threadIdx.x;     // granule = 8 floats (1 chunk)
        int c  = gid & 15;
        int r2 = (gid >> 4) & 63;              // packed (interleaved) row
        int T  = gid >> 10;                    // batch*32 + tile
        // packed row r2 = wh*32 + kt2*16 + l15 holds key-slot wh*32 + 2*l15 + kt2
        int slot = (r2 & 32) + 2 * (r2 & 15) + ((r2 >> 4) & 1);
        int j = (T & 31) * 64 + slot;
        int key = (j < cnt) ? idx[j] : 0;
        const float4* s4 = (const float4*)(K + ((size_t)(T >> 5) * LK_ + key) * DIM_ + c * 8);
        float4 a = s4[0], bq = s4[1];
        bf16x8 h = { (short)f2bf(a.x),  (short)f2bf(a.y),  (short)f2bf(a.z),  (short)f2bf(a.w),
                     (short)f2bf(bq.x), (short)f2bf(bq.y), (short)f2bf(bq.z), (short)f2bf(bq.w) };
        *(bf16x8*)(Kb + (size_t)T * 8192 + r2 * 128 + ((c ^ (r2 & 15)) * 8)) = h;
    } else {
        int T = bid - 2048;                    // batch*32 + tile
        int w = threadIdx.x >> 6, lane = threadIdx.x & 63;
        const float* vb = V + (size_t)(T >> 5) * LK_ * DIM_;
        const int* ix = idx + (T & 31) * 64;
        int jbase = (T & 31) * 64;
        unsigned short* db = Vtb + (size_t)T * 8192;
        #pragma unroll
        for (int half = 0; half < 2; ++half) {
            int d = half * 64 + lane;
            #pragma unroll
            for (int cb = 0; cb < 8; cb += 4) {
                int c = cb + w;
                float v[8];
                #pragma unroll
                for (int kk = 0; kk < 8; ++kk) {
                    int j = c * 8 + kk;
                    int key = (jbase + j < cnt) ? ix[j] : 0;
                    v[kk] = vb[(size_t)key * DIM_ + d];   // coalesced over lanes (d)
                }
                bf16x8 h = { (short)f2bf(v[0]), (short)f2bf(v[1]), (short)f2bf(v[2]), (short)f2bf(v[3]),
                             (short)f2bf(v[4]), (short)f2bf(v[5]), (short)f2bf(v[6]), (short)f2bf(v[7]) };
                *(bf16x8*)(db + d * 64 + ((c ^ (d & 7)) * 8)) = h;
            }
        }
    }
}

// ---- main kernel ----
__global__ __launch_bounds__(NTH, 2) void attn_mfma5(
    const float* __restrict__ Q, const unsigned short* __restrict__ Kb,
    const unsigned short* __restrict__ Vtb, const int* __restrict__ hdr,
    float* __restrict__ O)
{
    __shared__ __align__(16) unsigned short sKa[8192];
    __shared__ __align__(16) unsigned short sVta[8192];
    __shared__ __align__(16) unsigned short sKb_[8192];
    __shared__ __align__(16) unsigned short sVtb_[8192];
    __shared__ __align__(16) unsigned short sP[64 * PS];   // also Q staging
    __shared__ float sLp[64];

    const int tid  = threadIdx.x;
    const int w    = tid >> 6, lane = tid & 63;
    const int quad = lane >> 4, l15 = lane & 15;
    const int rg   = (w & 1) * 32;     // row group base
    const int wh   = w >> 1;           // key half
    const int kh   = wh * 32;

    const int bid = blockIdx.x;
    const int grp = bid >> 3;
    const int b   = (bid & 7) + 8 * (grp & 1);   // XCD-aware
    const int q0  = (grp >> 1) * 64;

    const int cnt = hdr[0];
    const int nIter2 = (((cnt + 63) >> 6) + 1) & ~1;   // even # of 64-key tiles

    bf16x8 vone;
    #pragma unroll
    for (int j = 0; j < 8; ++j) vone[j] = (short)0x3F80;

    // ---- stage Q (pre-scaled by SC2_) in two 32-row halves through sP ----
    bf16x8 aQ[2][4];
    {
        const float4* Qg = (const float4*)(Q + ((size_t)b * LQ_ + q0) * DIM_);
        #pragma unroll
        for (int h = 0; h < 2; ++h) {
            #pragma unroll
            for (int it = 0; it < 4; ++it) {
                int i2 = tid + it * NTH;
                int r = i2 >> 5, c4 = i2 & 31;
                float4 v = Qg[(h * 32 + r) * 32 + c4];
                ushort4 hh = { f2bf(v.x * SC2_), f2bf(v.y * SC2_),
                               f2bf(v.z * SC2_), f2bf(v.w * SC2_) };
                *(ushort4*)&sP[r * 128 + (((c4 >> 1) ^ (r & 15)) * 8) + (c4 & 1) * 4] = hh;
            }
            __syncthreads();
            if ((rg >> 5) == h) {
                #pragma unroll
                for (int rs = 0; rs < 2; ++rs)
                    #pragma unroll
                    for (int ks = 0; ks < 4; ++ks)
                        aQ[rs][ks] = *(const bf16x8*)&sP[(rs * 16 + l15) * 128 +
                                                         (((ks * 4 + quad) ^ l15) * 8)];
            }
            __syncthreads();
        }
    }

    // ---- prefetch tile 0 into buffer A ----
    {
        const char* ksrc = (const char*)Kb  + (size_t)(b * 32) * 16384;
        const char* vsrc = (const char*)Vtb + (size_t)(b * 32) * 16384;
        #pragma unroll
        for (int j = 0; j < 4; ++j) {
            int o = (j * 4 + w) * 1024;
            GLDS(ksrc + o + lane * 16, (char*)sKa + o);
            GLDS(vsrc + o + lane * 16, (char*)sVta + o);
        }
    }
    __syncthreads();

    f32x4 acc[2][8], lacc[2];
    #pragma unroll
    for (int rs = 0; rs < 2; ++rs) {
        lacc[rs] = (f32x4){0.f, 0.f, 0.f, 0.f};
        #pragma unroll
        for (int dt = 0; dt < 8; ++dt) acc[rs][dt] = (f32x4){0.f, 0.f, 0.f, 0.f};
    }

#define TILE_BODY(CURK, CURV, NXTK, NXTV, I) do {                              \
    const int nxt = (I) + 1;                                                   \
    if (nxt < nIter2) {                                                        \
        const char* ksrc = (const char*)Kb  + (size_t)(b * 32 + nxt) * 16384;  \
        const char* vsrc = (const char*)Vtb + (size_t)(b * 32 + nxt) * 16384;  \
        _Pragma("unroll")                                                      \
        for (int j = 0; j < 4; ++j) {                                          \
            int o = (j * 4 + w) * 1024;                                        \
            GLDS(ksrc + o + lane * 16, (char*)(NXTK) + o);                     \
            GLDS(vsrc + o + lane * 16, (char*)(NXTV) + o);                     \
        }                                                                      \
    }                                                                          \
    f32x4 s_[2][2];                                                            \
    _Pragma("unroll")                                                          \
    for (int kt2 = 0; kt2 < 2; ++kt2) {                                        \
        f32x4 c0 = (f32x4){0.f,0.f,0.f,0.f}, c1 = (f32x4){0.f,0.f,0.f,0.f};   \
        _Pragma("unroll")                                                      \
        for (int ks = 0; ks < 4; ++ks) {                                       \
            bf16x8 bk = *(const bf16x8*)&(CURK)[(kh + kt2 * 16 + l15) * 128 +  \
                                                (((ks * 4 + quad) ^ l15) * 8)];\
            c0 = __builtin_amdgcn_mfma_f32_16x16x32_bf16(aQ[0][ks], bk, c0, 0,0,0); \
            c1 = __builtin_amdgcn_mfma_f32_16x16x32_bf16(aQ[1][ks], bk, c1, 0,0,0); \
        }                                                                      \
        int slot = (I) * 64 + kh + 2 * l15 + kt2;                              \
        float bias = (slot < cnt) ? CKEEP_ : CMASK_;                           \
        _Pragma("unroll")                                                      \
        for (int r = 0; r < 4; ++r) {                                          \
            s_[0][kt2][r] = c0[r] + bias;                                      \
            s_[1][kt2][r] = c1[r] + bias;                                      \
        }                                                                      \
    }                                                                          \
    _Pragma("unroll")                                                          \
    for (int rs = 0; rs < 2; ++rs)                                             \
        _Pragma("unroll")                                                      \
        for (int r = 0; r < 4; ++r) {                                          \
            float p0 = exp2f(s_[rs][0][r]);                                    \
            float p1 = exp2f(s_[rs][1][r]);                                    \
            int row = rg + rs * 16 + quad * 4 + r;                             \
            unsigned pk = __builtin_amdgcn_perm(                               \
                __builtin_bit_cast(unsigned, p1),                              \
                __builtin_bit_cast(unsigned, p0), 0x07060302u);                \
            *(unsigned*)&sP[row * PS + kh + 2 * l15] = pk;                     \
        }                                                                      \
    {                                                                          \
        bf16x8 aP0 = *(const bf16x8*)&sP[(rg + l15) * PS + kh + quad * 8];     \
        bf16x8 aP1 = *(const bf16x8*)&sP[(rg + 16 + l15) * PS + kh + quad * 8];\
        lacc[0] = __builtin_amdgcn_mfma_f32_16x16x32_bf16(aP0, vone, lacc[0], 0,0,0); \
        lacc[1] = __builtin_amdgcn_mfma_f32_16x16x32_bf16(aP1, vone, lacc[1], 0,0,0); \
        _Pragma("unroll")                                                      \
        for (int dt = 0; dt < 8; ++dt) {                                       \
            int d = dt * 16 + l15;                                             \
            bf16x8 bv = *(const bf16x8*)&(CURV)[d * 64 +                       \
                                        (((wh * 4 + quad) ^ (l15 & 7)) * 8)];  \
            acc[0][dt] = __builtin_amdgcn_mfma_f32_16x16x32_bf16(aP0, bv, acc[0][dt], 0,0,0); \
            acc[1][dt] = __builtin_amdgcn_mfma_f32_16x16x32_bf16(aP1, bv, acc[1][dt], 0,0,0); \
        }                                                                      \
    }                                                                          \
    __syncthreads();                                                           \
} while (0)

    for (int kk = 0; kk < nIter2; kk += 2) {
        TILE_BODY(sKa,  sVta,  sKb_, sVtb_, kk);
        TILE_BODY(sKb_, sVtb_, sKa,  sVta,  kk + 1);
    }
#undef TILE_BODY

    // ---- epilogue: combine key-half partials (wh=1 publishes via LDS) ----
    float* sOw = (rg == 0) ? (float*)sKa : (float*)sVta;   // 32 rows x 128 f32
    if (wh == 1) {
        #pragma unroll
        for (int rs = 0; rs < 2; ++rs)
            #pragma unroll
            for (int r = 0; r < 4; ++r) {
                int lrow = rs * 16 + quad * 4 + r;
                #pragma unroll
                for (int dt = 0; dt < 8; ++dt)
                    sOw[lrow * 128 + dt * 16 + l15] = acc[rs][dt][r];
                if (l15 == 0) sLp[rg + lrow] = lacc[rs][r];
            }
    }
    __syncthreads();
    if (wh == 0) {
        float* Og = O + ((size_t)b * LQ_ + q0 + rg) * DIM_;
        #pragma unroll
        for (int rs = 0; rs < 2; ++rs)
            #pragma unroll
            for (int r = 0; r < 4; ++r) {
                int lrow = rs * 16 + quad * 4 + r;
                float inv = 1.0f / (lacc[rs][r] + sLp[rg + lrow]);
                #pragma unroll
                for (int dt = 0; dt < 8; ++dt)
                    Og[(size_t)lrow * DIM_ + dt * 16 + l15] =
                        (acc[rs][dt][r] + sOw[lrow * 128 + dt * 16 + l15]) * inv;
            }
    }
}

// ================= fallback (validated R1 kernel, ws too small) =============
#define QS 136
#define VS 72
__global__ __launch_bounds__(NTH, 2) void attn_fallback(
    const float* __restrict__ Q, const float* __restrict__ K,
    const float* __restrict__ V, const float* __restrict__ Mk,
    float* __restrict__ O)
{
    __shared__ __align__(16) unsigned short sQ[64][QS];
    __shared__ __align__(16) unsigned short sK[64][QS];
    __shared__ __align__(16) unsigned short sVt[DIM_][VS];
    __shared__ __align__(16) unsigned short sPf[64][VS];
    __shared__ float sB[64];

    const int tid  = threadIdx.x;
    const int w    = tid >> 6, lane = tid & 63;
    const int quad = lane >> 4, l15 = lane & 15;
    const int bid = blockIdx.x;
    const int grp = bid >> 3;
    const int b   = (bid & 7) + 8 * (grp & 1);
    const int q0  = (grp >> 1) * 64;

    {
        const float4* Qg = (const float4*)(Q + ((size_t)b * LQ_ + q0) * DIM_);
        #pragma unroll
        for (int it = 0; it < 8; ++it) {
            int i = tid + it * NTH;
            int r = i >> 5, c4 = i & 31;
            float4 v = Qg[r * 32 + c4];
            ushort4 h = { f2bf(v.x), f2bf(v.y), f2bf(v.z), f2bf(v.w) };
            *(ushort4*)&sQ[r][c4 * 4] = h;
        }
    }
    __syncthreads();
    bf16x8 aQ[4];
    #pragma unroll
    for (int ks = 0; ks < 4; ++ks)
        aQ[ks] = *(const bf16x8*)&sQ[w * 16 + l15][ks * 32 + quad * 8];

    float m_i[4], l_i[4];
    f32x4 acc[8];
    #pragma unroll
    for (int r = 0; r < 4; ++r) { m_i[r] = -3.0e38f; l_i[r] = 0.f; }
    #pragma unroll
    for (int dt = 0; dt < 8; ++dt) acc[dt] = (f32x4){0.f, 0.f, 0.f, 0.f};

    for (int k0 = 0; k0 < LK_; k0 += 64) {
        const float4* Kg = (const float4*)(K + ((size_t)b * LK_ + k0) * DIM_);
        const float4* Vg = (const float4*)(V + ((size_t)b * LK_ + k0) * DIM_);
        #pragma unroll
        for (int it = 0; it < 8; ++it) {
            int i = tid + it * NTH;
            int r = i >> 5, c4 = i & 31;
            float4 kv = Kg[r * 32 + c4];
            ushort4 h = { f2bf(kv.x), f2bf(kv.y), f2bf(kv.z), f2bf(kv.w) };
            *(ushort4*)&sK[r][c4 * 4] = h;
            float4 vv = Vg[r * 32 + c4];
            int d = c4 * 4;
            sVt[d + 0][r] = f2bf(vv.x);
            sVt[d + 1][r] = f2bf(vv.y);
            sVt[d + 2][r] = f2bf(vv.z);
            sVt[d + 3][r] = f2bf(vv.w);
        }
        if (tid < 64) sB[tid] = Mk[k0 + tid] * NEGBIG;
        __syncthreads();

        f32x4 s[4];
        #pragma unroll
        for (int kt = 0; kt < 4; ++kt) {
            f32x4 c = (f32x4){0.f, 0.f, 0.f, 0.f};
            #pragma unroll
            for (int ks = 0; ks < 4; ++ks) {
                bf16x8 bk = *(const bf16x8*)&sK[kt * 16 + l15][ks * 32 + quad * 8];
                c = __builtin_amdgcn_mfma_f32_16x16x32_bf16(aQ[ks], bk, c, 0, 0, 0);
            }
            float bias = sB[kt * 16 + l15];
            #pragma unroll
            for (int r = 0; r < 4; ++r) s[kt][r] = c[r] * SCALE_ + bias;
        }
        #pragma unroll
        for (int r = 0; r < 4; ++r) {
            float mx = fmaxf(fmaxf(s[0][r], s[1][r]), fmaxf(s[2][r], s[3][r]));
            #pragma unroll
            for (int off = 1; off < 16; off <<= 1) mx = fmaxf(mx, __shfl_xor(mx, off));
            float mn = fmaxf(m_i[r], mx);
            float al = __expf(m_i[r] - mn);
            m_i[r] = mn;
            float rsum = 0.f;
            #pragma unroll
            for (int kt = 0; kt < 4; ++kt) {
                float p = __expf(s[kt][r] - mn);
                rsum += p;
                sPf[w * 16 + quad * 4 + r][kt * 16 + l15] = f2bf(p);
            }
            #pragma unroll
            for (int off = 1; off < 16; off <<= 1) rsum += __shfl_xor(rsum, off);
            l_i[r] = l_i[r] * al + rsum;
            #pragma unroll
            for (int dt = 0; dt < 8; ++dt) acc[dt][r] *= al;
        }
        bf16x8 aP0 = *(const bf16x8*)&sPf[w * 16 + l15][quad * 8];
        bf16x8 aP1 = *(const bf16x8*)&sPf[w * 16 + l15][32 + quad * 8];
        #pragma unroll
        for (int dt = 0; dt < 8; ++dt) {
            bf16x8 bv0 = *(const bf16x8*)&sVt[dt * 16 + l15][quad * 8];
            bf16x8 bv1 = *(const bf16x8*)&sVt[dt * 16 + l15][32 + quad * 8];
            acc[dt] = __builtin_amdgcn_mfma_f32_16x16x32_bf16(aP0, bv0, acc[dt], 0, 0, 0);
            acc[dt] = __builtin_amdgcn_mfma_f32_16x16x32_bf16(aP1, bv1, acc[dt], 0, 0, 0);
        }
        __syncthreads();
    }
    float* Og = O + ((size_t)b * LQ_ + q0 + w * 16) * DIM_;
    #pragma unroll
    for (int r = 0; r < 4; ++r) {
        float inv = 1.0f / l_i[r];
        int row = quad * 4 + r;
        #pragma unroll
        for (int dt = 0; dt < 8; ++dt)
            Og[(size_t)row * DIM_ + dt * 16 + l15] = acc[dt][r] * inv;
    }
}

extern "C" void kernel_launch(void* const* d_in, const int* in_sizes, int n_in,
                              void* d_out, int out_size, void* d_ws, size_t ws_size,
                              hipStream_t stream)
{
    const float* Q  = (const float*)d_in[0];
    const float* K  = (const float*)d_in[1];
    const float* V  = (const float*)d_in[2];
    const float* Mk = (const float*)d_in[3];
    float* O = (float*)d_out;

    const size_t seg  = (size_t)B_ * LK_ * DIM_ * 2;   // 8 MB per packed tensor
    const size_t need = 16384 + 2 * seg;               // hdr+idx + Kb + Vtb
    if (ws_size >= need) {
        int* hdr = (int*)d_ws;                          // [0] = kept count
        int* idx = hdr + 16;                            // 2048 ints
        unsigned short* Kb  = (unsigned short*)((char*)d_ws + 16384);
        unsigned short* Vtb = Kb + seg / 2;
        hipLaunchKernelGGL(build_idx, dim3(1),    dim3(256), 0, stream, Mk, hdr, idx);
        hipLaunchKernelGGL(pack_kv,   dim3(2560), dim3(NTH), 0, stream, K, V, hdr, idx, Kb, Vtb);
        hipLaunchKernelGGL(attn_mfma5, dim3(512), dim3(NTH), 0, stream, Q, Kb, Vtb, hdr, O);
    } else {
        hipLaunchKernelGGL(attn_fallback, dim3(512), dim3(NTH), 0, stream, Q, K, V, Mk, O);
    }
}

// Round 7
// 144.487 us; speedup vs baseline: 6.5584x; 1.0459x over previous
//
#include <hip/hip_runtime.h>
#include <hip/hip_bf16.h>

// R7: bf16-MFMA flash attention; V served from global (no V LDS buffers).
// - K: masked-key-compacted, key-interleaved, XOR-swizzled bf16 tiles in ws,
//   double-buffered in LDS via global_load_lds (R6 pipeline).
// - V: packed V^T tiles laid out so each PV B-frag is 16 contiguous bytes;
//   bv loaded global->VGPR (1KB coalesced/inst, L2-hot). LDS 75->42 KB,
//   LDS pipe traffic ~2400->~1400 cyc/CU-iter.
// - exp2 via __builtin_amdgcn_exp2f; fixed-max shift dropped (cancels in
//   normalization): s = kept ? qk : -1e30 (cndmask), p = exp2(s).

#define B_    16
#define LQ_   2048
#define LK_   2048
#define DIM_  128
#define NTH   256
#define SCALE_ 0.08838834764831845f          // 1/sqrt(128)
#define LOG2E_ 1.4426950408889634f
#define SC2_   (SCALE_ * LOG2E_)
#define NEGBIG -1.0e9f
#define PS 72                                 // sP row stride (ushorts)

typedef __attribute__((ext_vector_type(8))) short bf16x8;
typedef __attribute__((ext_vector_type(4))) float f32x4;

#define GLDS(gsrc, ldst) \
  __builtin_amdgcn_global_load_lds( \
      (const __attribute__((address_space(1))) unsigned int*)(gsrc), \
      (__attribute__((address_space(3))) unsigned int*)(ldst), 16, 0, 0)

static __device__ __forceinline__ unsigned short f2bf(float f) {
    unsigned int u = __builtin_bit_cast(unsigned int, f);
    u += 0x7fff + ((u >> 16) & 1);          // RNE
    return (unsigned short)(u >> 16);
}

// ---- kernel 1: kept-key index list (mask==0 kept), 1 block ----
__global__ __launch_bounds__(256) void build_idx(const float* __restrict__ Mk,
                                                 int* __restrict__ hdr,
                                                 int* __restrict__ idx)
{
    __shared__ int sc[256];
    int t = threadIdx.x;
    int keep[8], loc[8];
    int c = 0;
    #pragma unroll
    for (int j = 0; j < 8; ++j) {
        keep[j] = (Mk[t * 8 + j] < 0.5f) ? 1 : 0;
        loc[j] = c;
        c += keep[j];
    }
    sc[t] = c;
    __syncthreads();
    for (int off = 1; off < 256; off <<= 1) {
        int v = (t >= off) ? sc[t - off] : 0;
        __syncthreads();
        sc[t] += v;
        __syncthreads();
    }
    int base = sc[t] - c;
    #pragma unroll
    for (int j = 0; j < 8; ++j)
        if (keep[j]) idx[base + loc[j]] = t * 8 + j;
    if (t == 255) hdr[0] = sc[255];
}

// ---- kernel 2: gather-pack kept K rows (key-interleaved, chunk^row swizzle)
//      + V^T tiles: layout off = kc*4096 + d*32 + (c&3)*8 (kc = key-half),
//      so PV frag (16 rows x 16B) is 1KB contiguous per instruction. ----
__global__ __launch_bounds__(NTH) void pack_kv(
    const float* __restrict__ K, const float* __restrict__ V,
    const int* __restrict__ hdr, const int* __restrict__ idx,
    unsigned short* __restrict__ Kb, unsigned short* __restrict__ Vtb)
{
    const int cnt = hdr[0];
    int bid = blockIdx.x;
    if (bid < 2048) {
        int gid = bid * NTH + threadIdx.x;     // granule = 8 floats (1 chunk)
        int c  = gid & 15;
        int r2 = (gid >> 4) & 63;              // packed (interleaved) row
        int T  = gid >> 10;                    // batch*32 + tile
        int slot = (r2 & 32) + 2 * (r2 & 15) + ((r2 >> 4) & 1);
        int j = (T & 31) * 64 + slot;
        int key = (j < cnt) ? idx[j] : 0;
        const float4* s4 = (const float4*)(K + ((size_t)(T >> 5) * LK_ + key) * DIM_ + c * 8);
        float4 a = s4[0], bq = s4[1];
        bf16x8 h = { (short)f2bf(a.x),  (short)f2bf(a.y),  (short)f2bf(a.z),  (short)f2bf(a.w),
                     (short)f2bf(bq.x), (short)f2bf(bq.y), (short)f2bf(bq.z), (short)f2bf(bq.w) };
        *(bf16x8*)(Kb + (size_t)T * 8192 + r2 * 128 + ((c ^ (r2 & 15)) * 8)) = h;
    } else {
        int T = bid - 2048;                    // batch*32 + tile
        int w4 = threadIdx.x >> 6, lane = threadIdx.x & 63;
        const float* vb = V + (size_t)(T >> 5) * LK_ * DIM_;
        const int* ix = idx + (T & 31) * 64;
        int jbase = (T & 31) * 64;
        unsigned short* db = Vtb + (size_t)T * 8192;
        #pragma unroll
        for (int half = 0; half < 2; ++half) {
            int d = half * 64 + lane;
            #pragma unroll
            for (int cb = 0; cb < 8; cb += 4) {
                int c = cb + w4;               // chunk of 8 keys, c in 0..7
                float v[8];
                #pragma unroll
                for (int kk = 0; kk < 8; ++kk) {
                    int j = c * 8 + kk;
                    int key = (jbase + j < cnt) ? ix[j] : 0;
                    v[kk] = vb[(size_t)key * DIM_ + d];   // coalesced over lanes (d)
                }
                bf16x8 h = { (short)f2bf(v[0]), (short)f2bf(v[1]), (short)f2bf(v[2]), (short)f2bf(v[3]),
                             (short)f2bf(v[4]), (short)f2bf(v[5]), (short)f2bf(v[6]), (short)f2bf(v[7]) };
                *(bf16x8*)(db + (c >> 2) * 4096 + d * 32 + (c & 3) * 8) = h;
            }
        }
    }
}

// ---- main kernel ----
__global__ __launch_bounds__(NTH, 2) void attn_mfma6(
    const float* __restrict__ Q, const unsigned short* __restrict__ Kb,
    const unsigned short* __restrict__ Vtb, const int* __restrict__ hdr,
    float* __restrict__ O)
{
    __shared__ __align__(16) unsigned short sKa[8192];     // 16 KB
    __shared__ __align__(16) unsigned short sKb_[8192];    // 16 KB
    __shared__ __align__(16) unsigned short sP[64 * PS];   // 9.2 KB, also Q staging
    __shared__ float sLp[64];

    const int tid  = threadIdx.x;
    const int w    = tid >> 6, lane = tid & 63;
    const int quad = lane >> 4, l15 = lane & 15;
    const int rg   = (w & 1) * 32;     // row group base
    const int wh   = w >> 1;           // key half
    const int kh   = wh * 32;

    const int bid = blockIdx.x;
    const int grp = bid >> 3;
    const int b   = (bid & 7) + 8 * (grp & 1);   // XCD-aware
    const int q0  = (grp >> 1) * 64;

    const int cnt = hdr[0];
    const int nIter2 = (((cnt + 63) >> 6) + 1) & ~1;   // even # of 64-key tiles

    bf16x8 vone;
    #pragma unroll
    for (int j = 0; j < 8; ++j) vone[j] = (short)0x3F80;

    // per-lane V-frag base offset (ushorts) within a tile
    const int voff = wh * 4096 + l15 * 32 + quad * 8;

    // ---- stage Q (pre-scaled by SC2_) in two 32-row halves through sP ----
    bf16x8 aQ[2][4];
    {
        const float4* Qg = (const float4*)(Q + ((size_t)b * LQ_ + q0) * DIM_);
        #pragma unroll
        for (int h = 0; h < 2; ++h) {
            #pragma unroll
            for (int it = 0; it < 4; ++it) {
                int i2 = tid + it * NTH;
                int r = i2 >> 5, c4 = i2 & 31;
                float4 v = Qg[(h * 32 + r) * 32 + c4];
                ushort4 hh = { f2bf(v.x * SC2_), f2bf(v.y * SC2_),
                               f2bf(v.z * SC2_), f2bf(v.w * SC2_) };
                *(ushort4*)&sP[r * 128 + (((c4 >> 1) ^ (r & 15)) * 8) + (c4 & 1) * 4] = hh;
            }
            __syncthreads();
            if ((rg >> 5) == h) {
                #pragma unroll
                for (int rs = 0; rs < 2; ++rs)
                    #pragma unroll
                    for (int ks = 0; ks < 4; ++ks)
                        aQ[rs][ks] = *(const bf16x8*)&sP[(rs * 16 + l15) * 128 +
                                                         (((ks * 4 + quad) ^ l15) * 8)];
            }
            __syncthreads();
        }
    }

    // ---- prefetch K tile 0 into buffer A ----
    {
        const char* ksrc = (const char*)Kb + (size_t)(b * 32) * 16384;
        #pragma unroll
        for (int j = 0; j < 4; ++j) {
            int o = (j * 4 + w) * 1024;
            GLDS(ksrc + o + lane * 16, (char*)sKa + o);
        }
    }
    __syncthreads();

    f32x4 acc[2][8], lacc[2];
    #pragma unroll
    for (int rs = 0; rs < 2; ++rs) {
        lacc[rs] = (f32x4){0.f, 0.f, 0.f, 0.f};
        #pragma unroll
        for (int dt = 0; dt < 8; ++dt) acc[rs][dt] = (f32x4){0.f, 0.f, 0.f, 0.f};
    }

#define TILE_BODY(CURK, NXTK, I) do {                                          \
    /* V fragments for THIS tile: global->VGPR, fully coalesced, L2-hot */     \
    const unsigned short* vsrc = Vtb + (size_t)(b * 32 + (I)) * 8192 + voff;   \
    bf16x8 bv[8];                                                              \
    _Pragma("unroll")                                                          \
    for (int dt = 0; dt < 8; ++dt) bv[dt] = *(const bf16x8*)(vsrc + dt * 512); \
    const int nxt = (I) + 1;                                                   \
    if (nxt < nIter2) {                                                        \
        const char* ksrc = (const char*)Kb + (size_t)(b * 32 + nxt) * 16384;   \
        _Pragma("unroll")                                                      \
        for (int j = 0; j < 4; ++j) {                                          \
            int o = (j * 4 + w) * 1024;                                        \
            GLDS(ksrc + o + lane * 16, (char*)(NXTK) + o);                     \
        }                                                                      \
    }                                                                          \
    f32x4 s_[2][2];                                                            \
    _Pragma("unroll")                                                          \
    for (int kt2 = 0; kt2 < 2; ++kt2) {                                        \
        f32x4 c0 = (f32x4){0.f,0.f,0.f,0.f}, c1 = (f32x4){0.f,0.f,0.f,0.f};   \
        _Pragma("unroll")                                                      \
        for (int ks = 0; ks < 4; ++ks) {                                       \
            bf16x8 bk = *(const bf16x8*)&(CURK)[(kh + kt2 * 16 + l15) * 128 +  \
                                                (((ks * 4 + quad) ^ l15) * 8)];\
            c0 = __builtin_amdgcn_mfma_f32_16x16x32_bf16(aQ[0][ks], bk, c0, 0,0,0); \
            c1 = __builtin_amdgcn_mfma_f32_16x16x32_bf16(aQ[1][ks], bk, c1, 0,0,0); \
        }                                                                      \
        int slot = (I) * 64 + kh + 2 * l15 + kt2;                              \
        bool kept = slot < cnt;                                                \
        _Pragma("unroll")                                                      \
        for (int r = 0; r < 4; ++r) {                                          \
            s_[0][kt2][r] = kept ? c0[r] : -1.0e30f;                           \
            s_[1][kt2][r] = kept ? c1[r] : -1.0e30f;                           \
        }                                                                      \
    }                                                                          \
    _Pragma("unroll")                                                          \
    for (int rs = 0; rs < 2; ++rs)                                             \
        _Pragma("unroll")                                                      \
        for (int r = 0; r < 4; ++r) {                                          \
            float p0 = __builtin_amdgcn_exp2f(s_[rs][0][r]);                   \
            float p1 = __builtin_amdgcn_exp2f(s_[rs][1][r]);                   \
            int row = rg + rs * 16 + quad * 4 + r;                             \
            unsigned pk = __builtin_amdgcn_perm(                               \
                __builtin_bit_cast(unsigned, p1),                              \
                __builtin_bit_cast(unsigned, p0), 0x07060302u);                \
            *(unsigned*)&sP[row * PS + kh + 2 * l15] = pk;                     \
        }                                                                      \
    {                                                                          \
        bf16x8 aP0 = *(const bf16x8*)&sP[(rg + l15) * PS + kh + quad * 8];     \
        bf16x8 aP1 = *(const bf16x8*)&sP[(rg + 16 + l15) * PS + kh + quad * 8];\
        lacc[0] = __builtin_amdgcn_mfma_f32_16x16x32_bf16(aP0, vone, lacc[0], 0,0,0); \
        lacc[1] = __builtin_amdgcn_mfma_f32_16x16x32_bf16(aP1, vone, lacc[1], 0,0,0); \
        _Pragma("unroll")                                                      \
        for (int dt = 0; dt < 8; ++dt) {                                       \
            acc[0][dt] = __builtin_amdgcn_mfma_f32_16x16x32_bf16(aP0, bv[dt], acc[0][dt], 0,0,0); \
            acc[1][dt] = __builtin_amdgcn_mfma_f32_16x16x32_bf16(aP1, bv[dt], acc[1][dt], 0,0,0); \
        }                                                                      \
    }                                                                          \
    __syncthreads();                                                           \
} while (0)

    for (int kk = 0; kk < nIter2; kk += 2) {
        TILE_BODY(sKa,  sKb_, kk);
        TILE_BODY(sKb_, sKa,  kk + 1);
    }
#undef TILE_BODY

    // ---- epilogue: combine key-half partials (wh=1 publishes via LDS) ----
    float* sOw = (rg == 0) ? (float*)sKa : (float*)sKb_;   // 32 rows x 128 f32
    if (wh == 1) {
        #pragma unroll
        for (int rs = 0; rs < 2; ++rs)
            #pragma unroll
            for (int r = 0; r < 4; ++r) {
                int lrow = rs * 16 + quad * 4 + r;
                #pragma unroll
                for (int dt = 0; dt < 8; ++dt)
                    sOw[lrow * 128 + dt * 16 + l15] = acc[rs][dt][r];
                if (l15 == 0) sLp[rg + lrow] = lacc[rs][r];
            }
    }
    __syncthreads();
    if (wh == 0) {
        float* Og = O + ((size_t)b * LQ_ + q0 + rg) * DIM_;
        #pragma unroll
        for (int rs = 0; rs < 2; ++rs)
            #pragma unroll
            for (int r = 0; r < 4; ++r) {
                int lrow = rs * 16 + quad * 4 + r;
                float inv = 1.0f / (lacc[rs][r] + sLp[rg + lrow]);
                #pragma unroll
                for (int dt = 0; dt < 8; ++dt)
                    Og[(size_t)lrow * DIM_ + dt * 16 + l15] =
                        (acc[rs][dt][r] + sOw[lrow * 128 + dt * 16 + l15]) * inv;
            }
    }
}

// ================= fallback (validated R1 kernel, ws too small) =============
#define QS 136
#define VS 72
__global__ __launch_bounds__(NTH, 2) void attn_fallback(
    const float* __restrict__ Q, const float* __restrict__ K,
    const float* __restrict__ V, const float* __restrict__ Mk,
    float* __restrict__ O)
{
    __shared__ __align__(16) unsigned short sQ[64][QS];
    __shared__ __align__(16) unsigned short sK[64][QS];
    __shared__ __align__(16) unsigned short sVt[DIM_][VS];
    __shared__ __align__(16) unsigned short sPf[64][VS];
    __shared__ float sB[64];

    const int tid  = threadIdx.x;
    const int w    = tid >> 6, lane = tid & 63;
    const int quad = lane >> 4, l15 = lane & 15;
    const int bid = blockIdx.x;
    const int grp = bid >> 3;
    const int b   = (bid & 7) + 8 * (grp & 1);
    const int q0  = (grp >> 1) * 64;

    {
        const float4* Qg = (const float4*)(Q + ((size_t)b * LQ_ + q0) * DIM_);
        #pragma unroll
        for (int it = 0; it < 8; ++it) {
            int i = tid + it * NTH;
            int r = i >> 5, c4 = i & 31;
            float4 v = Qg[r * 32 + c4];
            ushort4 h = { f2bf(v.x), f2bf(v.y), f2bf(v.z), f2bf(v.w) };
            *(ushort4*)&sQ[r][c4 * 4] = h;
        }
    }
    __syncthreads();
    bf16x8 aQ[4];
    #pragma unroll
    for (int ks = 0; ks < 4; ++ks)
        aQ[ks] = *(const bf16x8*)&sQ[w * 16 + l15][ks * 32 + quad * 8];

    float m_i[4], l_i[4];
    f32x4 acc[8];
    #pragma unroll
    for (int r = 0; r < 4; ++r) { m_i[r] = -3.0e38f; l_i[r] = 0.f; }
    #pragma unroll
    for (int dt = 0; dt < 8; ++dt) acc[dt] = (f32x4){0.f, 0.f, 0.f, 0.f};

    for (int k0 = 0; k0 < LK_; k0 += 64) {
        const float4* Kg = (const float4*)(K + ((size_t)b * LK_ + k0) * DIM_);
        const float4* Vg = (const float4*)(V + ((size_t)b * LK_ + k0) * DIM_);
        #pragma unroll
        for (int it = 0; it < 8; ++it) {
            int i = tid + it * NTH;
            int r = i >> 5, c4 = i & 31;
            float4 kv = Kg[r * 32 + c4];
            ushort4 h = { f2bf(kv.x), f2bf(kv.y), f2bf(kv.z), f2bf(kv.w) };
            *(ushort4*)&sK[r][c4 * 4] = h;
            float4 vv = Vg[r * 32 + c4];
            int d = c4 * 4;
            sVt[d + 0][r] = f2bf(vv.x);
            sVt[d + 1][r] = f2bf(vv.y);
            sVt[d + 2][r] = f2bf(vv.z);
            sVt[d + 3][r] = f2bf(vv.w);
        }
        if (tid < 64) sB[tid] = Mk[k0 + tid] * NEGBIG;
        __syncthreads();

        f32x4 s[4];
        #pragma unroll
        for (int kt = 0; kt < 4; ++kt) {
            f32x4 c = (f32x4){0.f, 0.f, 0.f, 0.f};
            #pragma unroll
            for (int ks = 0; ks < 4; ++ks) {
                bf16x8 bk = *(const bf16x8*)&sK[kt * 16 + l15][ks * 32 + quad * 8];
                c = __builtin_amdgcn_mfma_f32_16x16x32_bf16(aQ[ks], bk, c, 0, 0, 0);
            }
            float bias = sB[kt * 16 + l15];
            #pragma unroll
            for (int r = 0; r < 4; ++r) s[kt][r] = c[r] * SCALE_ + bias;
        }
        #pragma unroll
        for (int r = 0; r < 4; ++r) {
            float mx = fmaxf(fmaxf(s[0][r], s[1][r]), fmaxf(s[2][r], s[3][r]));
            #pragma unroll
            for (int off = 1; off < 16; off <<= 1) mx = fmaxf(mx, __shfl_xor(mx, off));
            float mn = fmaxf(m_i[r], mx);
            float al = __expf(m_i[r] - mn);
            m_i[r] = mn;
            float rsum = 0.f;
            #pragma unroll
            for (int kt = 0; kt < 4; ++kt) {
                float p = __expf(s[kt][r] - mn);
                rsum += p;
                sPf[w * 16 + quad * 4 + r][kt * 16 + l15] = f2bf(p);
            }
            #pragma unroll
            for (int off = 1; off < 16; off <<= 1) rsum += __shfl_xor(rsum, off);
            l_i[r] = l_i[r] * al + rsum;
            #pragma unroll
            for (int dt = 0; dt < 8; ++dt) acc[dt][r] *= al;
        }
        bf16x8 aP0 = *(const bf16x8*)&sPf[w * 16 + l15][quad * 8];
        bf16x8 aP1 = *(const bf16x8*)&sPf[w * 16 + l15][32 + quad * 8];
        #pragma unroll
        for (int dt = 0; dt < 8; ++dt) {
            bf16x8 bv0 = *(const bf16x8*)&sVt[dt * 16 + l15][quad * 8];
            bf16x8 bv1 = *(const bf16x8*)&sVt[dt * 16 + l15][32 + quad * 8];
            acc[dt] = __builtin_amdgcn_mfma_f32_16x16x32_bf16(aP0, bv0, acc[dt], 0, 0, 0);
            acc[dt] = __builtin_amdgcn_mfma_f32_16x16x32_bf16(aP1, bv1, acc[dt], 0, 0, 0);
        }
        __syncthreads();
    }
    float* Og = O + ((size_t)b * LQ_ + q0 + w * 16) * DIM_;
    #pragma unroll
    for (int r = 0; r < 4; ++r) {
        float inv = 1.0f / l_i[r];
        int row = quad * 4 + r;
        #pragma unroll
        for (int dt = 0; dt < 8; ++dt)
            Og[(size_t)row * DIM_ + dt * 16 + l15] = acc[dt][r] * inv;
    }
}

extern "C" void kernel_launch(void* const* d_in, const int* in_sizes, int n_in,
                              void* d_out, int out_size, void* d_ws, size_t ws_size,
                              hipStream_t stream)
{
    const float* Q  = (const float*)d_in[0];
    const float* K  = (const float*)d_in[1];
    const float* V  = (const float*)d_in[2];
    const float* Mk = (const float*)d_in[3];
    float* O = (float*)d_out;

    const size_t seg  = (size_t)B_ * LK_ * DIM_ * 2;   // 8 MB per packed tensor
    const size_t need = 16384 + 2 * seg;               // hdr+idx + Kb + Vtb
    if (ws_size >= need) {
        int* hdr = (int*)d_ws;                          // [0] = kept count
        int* idx = hdr + 16;                            // 2048 ints
        unsigned short* Kb  = (unsigned short*)((char*)d_ws + 16384);
        unsigned short* Vtb = Kb + seg / 2;
        hipLaunchKernelGGL(build_idx, dim3(1),    dim3(256), 0, stream, Mk, hdr, idx);
        hipLaunchKernelGGL(pack_kv,   dim3(2560), dim3(NTH), 0, stream, K, V, hdr, idx, Kb, Vtb);
        hipLaunchKernelGGL(attn_mfma6, dim3(512), dim3(NTH), 0, stream, Q, Kb, Vtb, hdr, O);
    } else {
        hipLaunchKernelGGL(attn_fallback, dim3(512), dim3(NTH), 0, stream, Q, K, V, Mk, O);
    }
}